// Round 16
// baseline (239.141 us; speedup 1.0000x reference)
//
#include <hip/hip_runtime.h>
#include <hip/hip_fp16.h>

#define NN 100000
#define NE 1600000
#define NEG_SLOPE 0.01f

#define NTL(x) __builtin_nontemporal_load(&(x))
typedef float fvec4 __attribute__((ext_vector_type(4)));
typedef float fvec2 __attribute__((ext_vector_type(2)));

// Coarse buckets: 256 consecutive dst nodes each.
#define NB     391        // ceil(NN/256)
#define TILE   4096       // edges per binning workgroup
#define NTILES 391        // ceil(NE/TILE)
#define CAP    8192       // LDS stage capacity per bucket

// gemm1: 2048 blocks x 4 waves = 8192 waves, ~12 rows each.
#define G1_BLOCKS 2048
#define G1_WAVES  (G1_BLOCKS * 4)

// ---------------------------------------------------------------------------
// Workspace layout (bytes) — total 26,008,384 B (< 26.4 MB proven).
//   offs  : (NN+1) int  @ 0          (400,004)
//   bcnt  : NB int      @ 400,384
//   boffs : (NB+1) int  @ 402,432
//   gcur  : NB int      @ 404,432
//   csrp  : NE int      @ 408,384    packed (src<<15 | w*32767), by dst, 6.4 MB
//   binned: NE int2     @ 6,808,384  bucket-grouped, 12.8 MB
//   Yq    : NN*64 fp8   @ 6,808,384  (ALIASES binned; binned dead before gemm1)
//   hw    : NN*32 fp16  @ 19,608,384 (6.4 MB)
#define OFF_BCNT  400384
#define OFF_BOFFS 402432
#define OFF_GCUR  404432
#define OFF_CSR   408384
#define OFF_YQ    6808384
#define OFF_HW    19608384

// ---------------------------------------------------------------------------
// A1: per-bucket edge counts (proven round 10).
__global__ __launch_bounds__(256) void k_bucketcnt(const int* __restrict__ dst,
                                                   int* __restrict__ bcnt)
{
    __shared__ int h[NB];
    int t = threadIdx.x;
    for (int i = t; i < NB; i += 256) h[i] = 0;
    __syncthreads();
    int base = blockIdx.x * TILE;
    for (int i = t; i < TILE; i += 256) {
        int e = base + i;
        if (e < NE) atomicAdd(&h[NTL(dst[e]) >> 8], 1);
    }
    __syncthreads();
    for (int i = t; i < NB; i += 256)
        if (h[i]) atomicAdd(&bcnt[i], h[i]);
}

// A2: exclusive scan of bucket counts (proven round 10).
__global__ __launch_bounds__(512) void k_bucketscan(const int* __restrict__ bcnt,
                                                    int* __restrict__ boffs,
                                                    int* __restrict__ gcur)
{
    __shared__ int lds[512];
    int t = threadIdx.x;
    int v = (t < NB) ? bcnt[t] : 0;
    lds[t] = v;
    __syncthreads();
    for (int off = 1; off < 512; off <<= 1) {
        int x = (t >= off) ? lds[t - off] : 0;
        __syncthreads();
        lds[t] += x;
        __syncthreads();
    }
    int excl = lds[t] - v;
    if (t < NB) { boffs[t] = excl; gcur[t] = excl; }
    if (t == NB - 1) boffs[NB] = lds[t];           // == NE
}

// A3: bin edges into bucket-grouped 'binned' (proven round 10).
__global__ __launch_bounds__(256) void k_binscatter(const int* __restrict__ dst,
                                                    const int* __restrict__ esrc,
                                                    const float* __restrict__ ew,
                                                    int* __restrict__ gcur,
                                                    int2* __restrict__ binned)
{
    __shared__ int   hist[NB];
    __shared__ int   cstart[NB];
    __shared__ int   ccur[NB];
    __shared__ int   gb[NB];
    __shared__ int   lds2[256];
    __shared__ int   sdst[TILE];
    __shared__ short sbuck[TILE];
    __shared__ int2  stage[TILE];

    int t = threadIdx.x;
    int base = blockIdx.x * TILE;
    int nvalid = NE - base; if (nvalid > TILE) nvalid = TILE;

    for (int i = t; i < NB; i += 256) hist[i] = 0;
    __syncthreads();
    for (int i = t; i < TILE; i += 256) {
        int e = base + i;
        int d = (e < NE) ? NTL(dst[e]) : -1;
        sdst[i] = d;
        if (d >= 0) atomicAdd(&hist[d >> 8], 1);
    }
    __syncthreads();

    int h0 = (2 * t     < NB) ? hist[2 * t]     : 0;
    int h1 = (2 * t + 1 < NB) ? hist[2 * t + 1] : 0;
    int ps = h0 + h1;
    lds2[t] = ps;
    __syncthreads();
    for (int off = 1; off < 256; off <<= 1) {
        int x = (t >= off) ? lds2[t - off] : 0;
        __syncthreads();
        lds2[t] += x;
        __syncthreads();
    }
    int excl = lds2[t] - ps;
    if (2 * t     < NB) { cstart[2 * t]     = excl;      ccur[2 * t]     = excl; }
    if (2 * t + 1 < NB) { cstart[2 * t + 1] = excl + h0; ccur[2 * t + 1] = excl + h0; }
    __syncthreads();

    for (int i = t; i < TILE; i += 256) {
        int d = sdst[i];
        if (d >= 0) {
            int e = base + i;
            int b = d >> 8;
            int pos = atomicAdd(&ccur[b], 1);
            stage[pos] = make_int2((NTL(esrc[e]) << 8) | (d & 255),
                                   __float_as_int(NTL(ew[e])));
            sbuck[pos] = (short)b;
        }
    }
    __syncthreads();

    for (int i = t; i < NB; i += 256)
        if (hist[i]) gb[i] = atomicAdd(&gcur[i], hist[i]);
    __syncthreads();
    for (int i = t; i < nvalid; i += 256) {
        int b = sbuck[i];
        binned[gb[b] + (i - cstart[b])] = stage[i];
    }
}

// B: per-bucket LDS counting sort -> csrp + offs (proven round 10).
__global__ __launch_bounds__(256) void k_bucketsort(const int2* __restrict__ binned,
                                                    const int* __restrict__ boffs,
                                                    int* __restrict__ offs,
                                                    int* __restrict__ csrp)
{
    __shared__ int nhist[256];
    __shared__ int nstart[256];
    __shared__ int ncur[256];
    __shared__ int lds[256];
    __shared__ int stage[CAP];

    int t = threadIdx.x, b = blockIdx.x;           // grid = NB
    int s0 = boffs[b], s1 = boffs[b + 1];
    int cnt = s1 - s0;

    nhist[t] = 0;
    __syncthreads();
    for (int i = t; i < cnt; i += 256)
        atomicAdd(&nhist[binned[s0 + i].x & 255], 1);
    __syncthreads();

    int v = nhist[t];
    lds[t] = v;
    __syncthreads();
    for (int off = 1; off < 256; off <<= 1) {
        int x = (t >= off) ? lds[t - off] : 0;
        __syncthreads();
        lds[t] += x;
        __syncthreads();
    }
    int excl = lds[t] - v;
    nstart[t] = excl;
    ncur[t] = excl;
    int node = b * 256 + t;
    if (node < NN) offs[node] = s0 + excl;
    if (b == NB - 1 && t == 0) offs[NN] = s1;      // == NE
    __syncthreads();

    for (int i = t; i < cnt; i += 256) {
        int2 r = binned[s0 + i];
        int dl = r.x & 255;
        unsigned src = ((unsigned)r.x) >> 8;
        float w = __int_as_float(r.y);
        unsigned wq = (unsigned)(w * 32767.0f + 0.5f);
        int pos = atomicAdd(&ncur[dl], 1);
        stage[pos] = (int)((src << 15) | wq);
    }
    __syncthreads();
    for (int i = t; i < cnt; i += 256)
        csrp[s0 + i] = stage[i];
}

// ---------------------------------------------------------------------------
// Y = feats @ W1 -> fp8 e4m3. W1 column in 64 VGPRs. The asm volatile makes
// each loaded value OPAQUE so LLVM cannot sink/rematerialize the W1 loads
// into the row loop (round 14/15: it did exactly that, VGPR=44, 80 us of
// VMEM-issue). 4 partial accumulators break the 64-deep serial FMA chain.
__global__ __launch_bounds__(256, 1) void k_gemm1(const float* __restrict__ feats,
                                                  const float* __restrict__ W1,
                                                  unsigned char* __restrict__ Yq)
{
    int lane = threadIdx.x & 63;
    int wid = (blockIdx.x * 256 + threadIdx.x) >> 6;

    float w[64];
    #pragma unroll
    for (int k = 0; k < 64; ++k) {
        w[k] = W1[k * 64 + lane];
        asm volatile("" : "+v"(w[k]));   // force true register residency
    }

    for (int r = wid; r < NN; r += G1_WAVES) {
        const float4* fr = (const float4*)(feats + r * 64);
        float p0 = 0.f, p1 = 0.f, p2 = 0.f, p3 = 0.f;
        #pragma unroll
        for (int i = 0; i < 16; ++i) {
            float4 v = fr[i];                    // wave-broadcast 16B load
            p0 = fmaf(v.x, w[4 * i + 0], p0);
            p1 = fmaf(v.y, w[4 * i + 1], p1);
            p2 = fmaf(v.z, w[4 * i + 2], p2);
            p3 = fmaf(v.w, w[4 * i + 3], p3);
        }
        float acc = (p0 + p1) + (p2 + p3);
        float accN = __shfl_xor(acc, 1, 64);
        int v01 = __builtin_amdgcn_cvt_pk_fp8_f32(acc, accN, 0, false);
        int v23 = __shfl_xor(v01, 2, 64);
        int word = (v01 & 0xFFFF) | (v23 << 16);
        if ((lane & 3) == 0)
            ((int*)(Yq + r * 64))[lane >> 2] = word;
    }
}

#define WDEC(c) ((float)((c) & 0x7fffu) * (1.0f / 32767.0f))

// ---------------------------------------------------------------------------
// Layer 1 (proven round 14): 4 edge-slots x 16 lanes x 4B fp8 gather; 8-shfl
// reduction; W2 in 32 VGPRs; h staged via 1 KB per-wave LDS.
__global__ __launch_bounds__(256) void k_l1(const int* __restrict__ offs,
                                            const int* __restrict__ csrp,
                                            const unsigned char* __restrict__ Yq,
                                            const float* __restrict__ b1,
                                            const float* __restrict__ W2,
                                            __half* __restrict__ hw)
{
    __shared__ __align__(16) float sh[4][64];      // per-wave h staging
    int tid = threadIdx.x;
    int lane = tid & 63;
    int wv = tid >> 6;
    int n = blockIdx.x * 4 + wv;                   // grid exact = NN waves
    int half = lane >> 5, c = lane & 31;

    float w2r[32];
    #pragma unroll
    for (int kk = 0; kk < 32; ++kk)
        w2r[kk] = W2[(half * 32 + kk) * 32 + c];

    int sub = lane >> 4;          // edge slot 0..3
    int e4  = lane & 15;          // col quad: cols [4*e4, 4*e4+4)
    const float4 bq = *(const float4*)(b1 + (e4 << 2));

    int start = offs[n], end = offs[n + 1];
    float a0 = 0.f, a1 = 0.f, a2 = 0.f, a3 = 0.f;
    for (int base = start; base < end; base += 64) {
        int m = end - base; if (m > 64) m = 64;
        int ed = (lane < m) ? NTL(csrp[base + lane]) : 0;   // pad: s=0, w=0
        int iters = (m + 3) >> 2;
        for (int i = 0; i < iters; ++i) {
            unsigned cc = (unsigned)__shfl(ed, (i << 2) + sub, 64);
            unsigned w8 = *(const unsigned*)(Yq + (cc >> 15) * 64 + (e4 << 2));
            float w = WDEC(cc);
            fvec2 lo = __builtin_amdgcn_cvt_pk_f32_fp8((int)w8, false);
            fvec2 hi = __builtin_amdgcn_cvt_pk_f32_fp8((int)w8, true);
            a0 = fmaf(w, lo.x, a0); a1 = fmaf(w, lo.y, a1);
            a2 = fmaf(w, hi.x, a2); a3 = fmaf(w, hi.y, a3);
        }
    }
    a0 += __shfl_xor(a0, 16, 64); a1 += __shfl_xor(a1, 16, 64);
    a2 += __shfl_xor(a2, 16, 64); a3 += __shfl_xor(a3, 16, 64);
    a0 += __shfl_xor(a0, 32, 64); a1 += __shfl_xor(a1, 32, 64);
    a2 += __shfl_xor(a2, 32, 64); a3 += __shfl_xor(a3, 32, 64);

    float h0 = a0 + bq.x, h1 = a1 + bq.y, h2 = a2 + bq.z, h3 = a3 + bq.w;
    h0 = h0 >= 0.f ? h0 : NEG_SLOPE * h0;  h1 = h1 >= 0.f ? h1 : NEG_SLOPE * h1;
    h2 = h2 >= 0.f ? h2 : NEG_SLOPE * h2;  h3 = h3 >= 0.f ? h3 : NEG_SLOPE * h3;

    if (sub == 0)
        *(float4*)&sh[wv][e4 << 2] = make_float4(h0, h1, h2, h3);
    __builtin_amdgcn_wave_barrier();               // keep write before reads

    float p = 0.f;
    #pragma unroll
    for (int q = 0; q < 8; ++q) {                  // broadcast reads, no conflicts
        float4 hv = *(const float4*)&sh[wv][(half << 5) + (q << 2)];
        p = fmaf(hv.x, w2r[4 * q + 0], p);
        p = fmaf(hv.y, w2r[4 * q + 1], p);
        p = fmaf(hv.z, w2r[4 * q + 2], p);
        p = fmaf(hv.w, w2r[4 * q + 3], p);
    }
    p += __shfl_xor(p, 32, 64);
    if (lane < 32) hw[n * 32 + lane] = __float2half(p);
}

// ---------------------------------------------------------------------------
// Layer 2 (proven round 14): 8 edge-slots x 8 lanes x 8B fp16; 12-shfl RED.
__global__ __launch_bounds__(256) void k_l2(const int* __restrict__ offs,
                                            const int* __restrict__ csrp,
                                            const __half* __restrict__ hw,
                                            const float* __restrict__ b2,
                                            float* __restrict__ out)
{
    int tid = threadIdx.x;
    int lane = tid & 63;
    int n = blockIdx.x * 4 + (tid >> 6);           // grid exact = NN waves
    int sub = lane >> 3;          // edge slot 0..7
    int e4  = lane & 7;           // col quad: cols [4*e4, 4*e4+4)
    const float4 bq = *(const float4*)(b2 + (e4 << 2));

    int start = offs[n], end = offs[n + 1];
    float a0 = 0.f, a1 = 0.f, a2 = 0.f, a3 = 0.f;
    for (int base = start; base < end; base += 64) {
        int m = end - base; if (m > 64) m = 64;
        int ed = (lane < m) ? NTL(csrp[base + lane]) : 0;   // pad: s=0, w=0
        int iters = (m + 7) >> 3;
        for (int i = 0; i < iters; ++i) {
            unsigned cc = (unsigned)__shfl(ed, (i << 3) + sub, 64);
            int2 raw = *(const int2*)(hw + (cc >> 15) * 32 + (e4 << 2));
            float w = WDEC(cc);
            float2 f0 = __half22float2(((const __half2*)&raw)[0]);
            float2 f1 = __half22float2(((const __half2*)&raw)[1]);
            a0 = fmaf(w, f0.x, a0); a1 = fmaf(w, f0.y, a1);
            a2 = fmaf(w, f1.x, a2); a3 = fmaf(w, f1.y, a3);
        }
    }
    a0 += __shfl_xor(a0,  8, 64); a1 += __shfl_xor(a1,  8, 64);
    a2 += __shfl_xor(a2,  8, 64); a3 += __shfl_xor(a3,  8, 64);
    a0 += __shfl_xor(a0, 16, 64); a1 += __shfl_xor(a1, 16, 64);
    a2 += __shfl_xor(a2, 16, 64); a3 += __shfl_xor(a3, 16, 64);
    a0 += __shfl_xor(a0, 32, 64); a1 += __shfl_xor(a1, 32, 64);
    a2 += __shfl_xor(a2, 32, 64); a3 += __shfl_xor(a3, 32, 64);

    if (sub == 0) {
        fvec4 o = { a0 + bq.x, a1 + bq.y, a2 + bq.z, a3 + bq.w };
        __builtin_nontemporal_store(o, (fvec4*)(out + n * 32 + (e4 << 2)));
    }
}

// ---------------------------------------------------------------------------
extern "C" void kernel_launch(void* const* d_in, const int* in_sizes, int n_in,
                              void* d_out, int out_size, void* d_ws, size_t ws_size,
                              hipStream_t stream)
{
    const float* feats = (const float*)d_in[0];
    const int*   esrc  = (const int*)d_in[1];
    const int*   edst  = (const int*)d_in[2];
    const float* ew    = (const float*)d_in[3];
    const float* W1    = (const float*)d_in[4];
    const float* b1    = (const float*)d_in[5];
    const float* W2    = (const float*)d_in[6];
    const float* b2    = (const float*)d_in[7];
    float* out = (float*)d_out;

    char*          ws     = (char*)d_ws;
    int*           offs   = (int*)ws;
    int*           bcnt   = (int*)(ws + OFF_BCNT);
    int*           boffs  = (int*)(ws + OFF_BOFFS);
    int*           gcur   = (int*)(ws + OFF_GCUR);
    int*           csrp   = (int*)(ws + OFF_CSR);
    int2*          binned = (int2*)(ws + OFF_YQ);  // aliases Yq; dead before gemm1
    unsigned char* Yq     = (unsigned char*)(ws + OFF_YQ);
    __half*        hw     = (__half*)(ws + OFF_HW);

    (void)hipMemsetAsync(bcnt, 0, NB * sizeof(int), stream);

    k_bucketcnt <<<NTILES,    256, 0, stream>>>(edst, bcnt);
    k_bucketscan<<<1,         512, 0, stream>>>(bcnt, boffs, gcur);
    k_binscatter<<<NTILES,    256, 0, stream>>>(edst, esrc, ew, gcur, binned);
    k_bucketsort<<<NB,        256, 0, stream>>>(binned, boffs, offs, csrp);
    k_gemm1     <<<G1_BLOCKS, 256, 0, stream>>>(feats, W1, Yq);
    k_l1        <<<NN / 4,    256, 0, stream>>>(offs, csrp, Yq, b1, W2, hw);
    k_l2        <<<NN / 4,    256, 0, stream>>>(offs, csrp, hw, b2, out);
}

// Round 17
// 217.810 us; speedup vs baseline: 1.0979x; 1.0979x over previous
//
#include <hip/hip_runtime.h>
#include <hip/hip_fp16.h>

#define NN 100000
#define NE 1600000
#define NEG_SLOPE 0.01f

#define NTL(x) __builtin_nontemporal_load(&(x))
typedef float fvec4 __attribute__((ext_vector_type(4)));
typedef float fvec2 __attribute__((ext_vector_type(2)));

// Coarse buckets: 256 consecutive dst nodes each.
#define NB     391        // ceil(NN/256)
#define TILE   4096       // edges per binning workgroup
#define NTILES 391        // ceil(NE/TILE)
#define CAP    8192       // LDS stage capacity per bucket

// gemm1: 8 rows per wave, 12500 waves = 3125 blocks (exact, 100000 = 12500*8).
#define G1_BLOCKS 3125

// ---------------------------------------------------------------------------
// Workspace layout (bytes) — total 26,008,384 B (< 26.4 MB proven).
//   offs  : (NN+1) int  @ 0          (400,004)
//   bcnt  : NB int      @ 400,384
//   boffs : (NB+1) int  @ 402,432
//   gcur  : NB int      @ 404,432
//   csrp  : NE int      @ 408,384    packed (src<<15 | w*32767), by dst, 6.4 MB
//   binned: NE int2     @ 6,808,384  bucket-grouped, 12.8 MB
//   Yq    : NN*64 fp8   @ 6,808,384  (ALIASES binned; binned dead before gemm1)
//   hw    : NN*32 fp16  @ 19,608,384 (6.4 MB)
#define OFF_BCNT  400384
#define OFF_BOFFS 402432
#define OFF_GCUR  404432
#define OFF_CSR   408384
#define OFF_YQ    6808384
#define OFF_HW    19608384

// ---------------------------------------------------------------------------
// A1: per-bucket edge counts (proven round 10).
__global__ __launch_bounds__(256) void k_bucketcnt(const int* __restrict__ dst,
                                                   int* __restrict__ bcnt)
{
    __shared__ int h[NB];
    int t = threadIdx.x;
    for (int i = t; i < NB; i += 256) h[i] = 0;
    __syncthreads();
    int base = blockIdx.x * TILE;
    for (int i = t; i < TILE; i += 256) {
        int e = base + i;
        if (e < NE) atomicAdd(&h[NTL(dst[e]) >> 8], 1);
    }
    __syncthreads();
    for (int i = t; i < NB; i += 256)
        if (h[i]) atomicAdd(&bcnt[i], h[i]);
}

// A2: exclusive scan of bucket counts (proven round 10).
__global__ __launch_bounds__(512) void k_bucketscan(const int* __restrict__ bcnt,
                                                    int* __restrict__ boffs,
                                                    int* __restrict__ gcur)
{
    __shared__ int lds[512];
    int t = threadIdx.x;
    int v = (t < NB) ? bcnt[t] : 0;
    lds[t] = v;
    __syncthreads();
    for (int off = 1; off < 512; off <<= 1) {
        int x = (t >= off) ? lds[t - off] : 0;
        __syncthreads();
        lds[t] += x;
        __syncthreads();
    }
    int excl = lds[t] - v;
    if (t < NB) { boffs[t] = excl; gcur[t] = excl; }
    if (t == NB - 1) boffs[NB] = lds[t];           // == NE
}

// A3: bin edges into bucket-grouped 'binned' (proven round 10).
__global__ __launch_bounds__(256) void k_binscatter(const int* __restrict__ dst,
                                                    const int* __restrict__ esrc,
                                                    const float* __restrict__ ew,
                                                    int* __restrict__ gcur,
                                                    int2* __restrict__ binned)
{
    __shared__ int   hist[NB];
    __shared__ int   cstart[NB];
    __shared__ int   ccur[NB];
    __shared__ int   gb[NB];
    __shared__ int   lds2[256];
    __shared__ int   sdst[TILE];
    __shared__ short sbuck[TILE];
    __shared__ int2  stage[TILE];

    int t = threadIdx.x;
    int base = blockIdx.x * TILE;
    int nvalid = NE - base; if (nvalid > TILE) nvalid = TILE;

    for (int i = t; i < NB; i += 256) hist[i] = 0;
    __syncthreads();
    for (int i = t; i < TILE; i += 256) {
        int e = base + i;
        int d = (e < NE) ? NTL(dst[e]) : -1;
        sdst[i] = d;
        if (d >= 0) atomicAdd(&hist[d >> 8], 1);
    }
    __syncthreads();

    int h0 = (2 * t     < NB) ? hist[2 * t]     : 0;
    int h1 = (2 * t + 1 < NB) ? hist[2 * t + 1] : 0;
    int ps = h0 + h1;
    lds2[t] = ps;
    __syncthreads();
    for (int off = 1; off < 256; off <<= 1) {
        int x = (t >= off) ? lds2[t - off] : 0;
        __syncthreads();
        lds2[t] += x;
        __syncthreads();
    }
    int excl = lds2[t] - ps;
    if (2 * t     < NB) { cstart[2 * t]     = excl;      ccur[2 * t]     = excl; }
    if (2 * t + 1 < NB) { cstart[2 * t + 1] = excl + h0; ccur[2 * t + 1] = excl + h0; }
    __syncthreads();

    for (int i = t; i < TILE; i += 256) {
        int d = sdst[i];
        if (d >= 0) {
            int e = base + i;
            int b = d >> 8;
            int pos = atomicAdd(&ccur[b], 1);
            stage[pos] = make_int2((NTL(esrc[e]) << 8) | (d & 255),
                                   __float_as_int(NTL(ew[e])));
            sbuck[pos] = (short)b;
        }
    }
    __syncthreads();

    for (int i = t; i < NB; i += 256)
        if (hist[i]) gb[i] = atomicAdd(&gcur[i], hist[i]);
    __syncthreads();
    for (int i = t; i < nvalid; i += 256) {
        int b = sbuck[i];
        binned[gb[b] + (i - cstart[b])] = stage[i];
    }
}

// B: per-bucket LDS counting sort -> csrp + offs (proven round 10).
__global__ __launch_bounds__(256) void k_bucketsort(const int2* __restrict__ binned,
                                                    const int* __restrict__ boffs,
                                                    int* __restrict__ offs,
                                                    int* __restrict__ csrp)
{
    __shared__ int nhist[256];
    __shared__ int nstart[256];
    __shared__ int ncur[256];
    __shared__ int lds[256];
    __shared__ int stage[CAP];

    int t = threadIdx.x, b = blockIdx.x;           // grid = NB
    int s0 = boffs[b], s1 = boffs[b + 1];
    int cnt = s1 - s0;

    nhist[t] = 0;
    __syncthreads();
    for (int i = t; i < cnt; i += 256)
        atomicAdd(&nhist[binned[s0 + i].x & 255], 1);
    __syncthreads();

    int v = nhist[t];
    lds[t] = v;
    __syncthreads();
    for (int off = 1; off < 256; off <<= 1) {
        int x = (t >= off) ? lds[t - off] : 0;
        __syncthreads();
        lds[t] += x;
        __syncthreads();
    }
    int excl = lds[t] - v;
    nstart[t] = excl;
    ncur[t] = excl;
    int node = b * 256 + t;
    if (node < NN) offs[node] = s0 + excl;
    if (b == NB - 1 && t == 0) offs[NN] = s1;      // == NE
    __syncthreads();

    for (int i = t; i < cnt; i += 256) {
        int2 r = binned[s0 + i];
        int dl = r.x & 255;
        unsigned src = ((unsigned)r.x) >> 8;
        float w = __int_as_float(r.y);
        unsigned wq = (unsigned)(w * 32767.0f + 0.5f);
        int pos = atomicAdd(&ncur[dl], 1);
        stage[pos] = (int)((src << 15) | wq);
    }
    __syncthreads();
    for (int i = t; i < cnt; i += 256)
        csrp[s0 + i] = stage[i];
}

// ---------------------------------------------------------------------------
// Y = feats @ W1 -> fp8 e4m3. Round-17 restructure: 8 ROWS PER WAVE so each
// W1 load feeds 8 FMAs — per-row VMEM drops 80 -> 24 regardless of whether
// the compiler keeps W1 resident (r14-r16: it refuses; VGPR stuck at 44).
// acc[8] uses only compile-time indices (stays in VGPRs).
__global__ __launch_bounds__(256) void k_gemm1(const float* __restrict__ feats,
                                               const float* __restrict__ W1,
                                               unsigned char* __restrict__ Yq)
{
    int lane = threadIdx.x & 63;
    int wid = (blockIdx.x * 256 + threadIdx.x) >> 6;   // 0..12499 (exact)
    int r0 = wid * 8;

    float acc[8] = {0.f, 0.f, 0.f, 0.f, 0.f, 0.f, 0.f, 0.f};

    for (int i = 0; i < 16; ++i) {                 // k-chunk of 4
        int k4 = i << 2;
        float w0 = W1[(k4 + 0) * 64 + lane];       // coalesced, 8 uses each
        float w1 = W1[(k4 + 1) * 64 + lane];
        float w2 = W1[(k4 + 2) * 64 + lane];
        float w3 = W1[(k4 + 3) * 64 + lane];
        #pragma unroll
        for (int j = 0; j < 8; ++j) {
            float4 v = *(const float4*)(feats + (r0 + j) * 64 + k4); // broadcast
            acc[j] = fmaf(v.x, w0, acc[j]);
            acc[j] = fmaf(v.y, w1, acc[j]);
            acc[j] = fmaf(v.z, w2, acc[j]);
            acc[j] = fmaf(v.w, w3, acc[j]);
        }
    }

    #pragma unroll
    for (int j = 0; j < 8; ++j) {                  // proven fp8 pack per row
        float a = acc[j];
        float aN = __shfl_xor(a, 1, 64);
        int v01 = __builtin_amdgcn_cvt_pk_fp8_f32(a, aN, 0, false);
        int v23 = __shfl_xor(v01, 2, 64);
        int word = (v01 & 0xFFFF) | (v23 << 16);
        if ((lane & 3) == 0)
            ((int*)(Yq + (r0 + j) * 64))[lane >> 2] = word;
    }
}

#define WDEC(c) ((float)((c) & 0x7fffu) * (1.0f / 32767.0f))

// ---------------------------------------------------------------------------
// Layer 1 (proven round 14): 4 edge-slots x 16 lanes x 4B fp8 gather; 8-shfl
// reduction; W2 in 32 VGPRs; h staged via 1 KB per-wave LDS.
__global__ __launch_bounds__(256) void k_l1(const int* __restrict__ offs,
                                            const int* __restrict__ csrp,
                                            const unsigned char* __restrict__ Yq,
                                            const float* __restrict__ b1,
                                            const float* __restrict__ W2,
                                            __half* __restrict__ hw)
{
    __shared__ __align__(16) float sh[4][64];      // per-wave h staging
    int tid = threadIdx.x;
    int lane = tid & 63;
    int wv = tid >> 6;
    int n = blockIdx.x * 4 + wv;                   // grid exact = NN waves
    int half = lane >> 5, c = lane & 31;

    float w2r[32];
    #pragma unroll
    for (int kk = 0; kk < 32; ++kk)
        w2r[kk] = W2[(half * 32 + kk) * 32 + c];

    int sub = lane >> 4;          // edge slot 0..3
    int e4  = lane & 15;          // col quad: cols [4*e4, 4*e4+4)
    const float4 bq = *(const float4*)(b1 + (e4 << 2));

    int start = offs[n], end = offs[n + 1];
    float a0 = 0.f, a1 = 0.f, a2 = 0.f, a3 = 0.f;
    for (int base = start; base < end; base += 64) {
        int m = end - base; if (m > 64) m = 64;
        int ed = (lane < m) ? NTL(csrp[base + lane]) : 0;   // pad: s=0, w=0
        int iters = (m + 3) >> 2;
        for (int i = 0; i < iters; ++i) {
            unsigned cc = (unsigned)__shfl(ed, (i << 2) + sub, 64);
            unsigned w8 = *(const unsigned*)(Yq + (cc >> 15) * 64 + (e4 << 2));
            float w = WDEC(cc);
            fvec2 lo = __builtin_amdgcn_cvt_pk_f32_fp8((int)w8, false);
            fvec2 hi = __builtin_amdgcn_cvt_pk_f32_fp8((int)w8, true);
            a0 = fmaf(w, lo.x, a0); a1 = fmaf(w, lo.y, a1);
            a2 = fmaf(w, hi.x, a2); a3 = fmaf(w, hi.y, a3);
        }
    }
    a0 += __shfl_xor(a0, 16, 64); a1 += __shfl_xor(a1, 16, 64);
    a2 += __shfl_xor(a2, 16, 64); a3 += __shfl_xor(a3, 16, 64);
    a0 += __shfl_xor(a0, 32, 64); a1 += __shfl_xor(a1, 32, 64);
    a2 += __shfl_xor(a2, 32, 64); a3 += __shfl_xor(a3, 32, 64);

    float h0 = a0 + bq.x, h1 = a1 + bq.y, h2 = a2 + bq.z, h3 = a3 + bq.w;
    h0 = h0 >= 0.f ? h0 : NEG_SLOPE * h0;  h1 = h1 >= 0.f ? h1 : NEG_SLOPE * h1;
    h2 = h2 >= 0.f ? h2 : NEG_SLOPE * h2;  h3 = h3 >= 0.f ? h3 : NEG_SLOPE * h3;

    if (sub == 0)
        *(float4*)&sh[wv][e4 << 2] = make_float4(h0, h1, h2, h3);
    __builtin_amdgcn_wave_barrier();               // keep write before reads

    float p = 0.f;
    #pragma unroll
    for (int q = 0; q < 8; ++q) {                  // broadcast reads, no conflicts
        float4 hv = *(const float4*)&sh[wv][(half << 5) + (q << 2)];
        p = fmaf(hv.x, w2r[4 * q + 0], p);
        p = fmaf(hv.y, w2r[4 * q + 1], p);
        p = fmaf(hv.z, w2r[4 * q + 2], p);
        p = fmaf(hv.w, w2r[4 * q + 3], p);
    }
    p += __shfl_xor(p, 32, 64);
    if (lane < 32) hw[n * 32 + lane] = __float2half(p);
}

// ---------------------------------------------------------------------------
// Layer 2 (proven round 14): 8 edge-slots x 8 lanes x 8B fp16; 12-shfl RED.
__global__ __launch_bounds__(256) void k_l2(const int* __restrict__ offs,
                                            const int* __restrict__ csrp,
                                            const __half* __restrict__ hw,
                                            const float* __restrict__ b2,
                                            float* __restrict__ out)
{
    int tid = threadIdx.x;
    int lane = tid & 63;
    int n = blockIdx.x * 4 + (tid >> 6);           // grid exact = NN waves
    int sub = lane >> 3;          // edge slot 0..7
    int e4  = lane & 7;           // col quad: cols [4*e4, 4*e4+4)
    const float4 bq = *(const float4*)(b2 + (e4 << 2));

    int start = offs[n], end = offs[n + 1];
    float a0 = 0.f, a1 = 0.f, a2 = 0.f, a3 = 0.f;
    for (int base = start; base < end; base += 64) {
        int m = end - base; if (m > 64) m = 64;
        int ed = (lane < m) ? NTL(csrp[base + lane]) : 0;   // pad: s=0, w=0
        int iters = (m + 7) >> 3;
        for (int i = 0; i < iters; ++i) {
            unsigned cc = (unsigned)__shfl(ed, (i << 3) + sub, 64);
            int2 raw = *(const int2*)(hw + (cc >> 15) * 32 + (e4 << 2));
            float w = WDEC(cc);
            float2 f0 = __half22float2(((const __half2*)&raw)[0]);
            float2 f1 = __half22float2(((const __half2*)&raw)[1]);
            a0 = fmaf(w, f0.x, a0); a1 = fmaf(w, f0.y, a1);
            a2 = fmaf(w, f1.x, a2); a3 = fmaf(w, f1.y, a3);
        }
    }
    a0 += __shfl_xor(a0,  8, 64); a1 += __shfl_xor(a1,  8, 64);
    a2 += __shfl_xor(a2,  8, 64); a3 += __shfl_xor(a3,  8, 64);
    a0 += __shfl_xor(a0, 16, 64); a1 += __shfl_xor(a1, 16, 64);
    a2 += __shfl_xor(a2, 16, 64); a3 += __shfl_xor(a3, 16, 64);
    a0 += __shfl_xor(a0, 32, 64); a1 += __shfl_xor(a1, 32, 64);
    a2 += __shfl_xor(a2, 32, 64); a3 += __shfl_xor(a3, 32, 64);

    if (sub == 0) {
        fvec4 o = { a0 + bq.x, a1 + bq.y, a2 + bq.z, a3 + bq.w };
        __builtin_nontemporal_store(o, (fvec4*)(out + n * 32 + (e4 << 2)));
    }
}

// ---------------------------------------------------------------------------
extern "C" void kernel_launch(void* const* d_in, const int* in_sizes, int n_in,
                              void* d_out, int out_size, void* d_ws, size_t ws_size,
                              hipStream_t stream)
{
    const float* feats = (const float*)d_in[0];
    const int*   esrc  = (const int*)d_in[1];
    const int*   edst  = (const int*)d_in[2];
    const float* ew    = (const float*)d_in[3];
    const float* W1    = (const float*)d_in[4];
    const float* b1    = (const float*)d_in[5];
    const float* W2    = (const float*)d_in[6];
    const float* b2    = (const float*)d_in[7];
    float* out = (float*)d_out;

    char*          ws     = (char*)d_ws;
    int*           offs   = (int*)ws;
    int*           bcnt   = (int*)(ws + OFF_BCNT);
    int*           boffs  = (int*)(ws + OFF_BOFFS);
    int*           gcur   = (int*)(ws + OFF_GCUR);
    int*           csrp   = (int*)(ws + OFF_CSR);
    int2*          binned = (int2*)(ws + OFF_YQ);  // aliases Yq; dead before gemm1
    unsigned char* Yq     = (unsigned char*)(ws + OFF_YQ);
    __half*        hw     = (__half*)(ws + OFF_HW);

    (void)hipMemsetAsync(bcnt, 0, NB * sizeof(int), stream);

    k_bucketcnt <<<NTILES,    256, 0, stream>>>(edst, bcnt);
    k_bucketscan<<<1,         512, 0, stream>>>(bcnt, boffs, gcur);
    k_binscatter<<<NTILES,    256, 0, stream>>>(edst, esrc, ew, gcur, binned);
    k_bucketsort<<<NB,        256, 0, stream>>>(binned, boffs, offs, csrp);
    k_gemm1     <<<G1_BLOCKS, 256, 0, stream>>>(feats, W1, Yq);
    k_l1        <<<NN / 4,    256, 0, stream>>>(offs, csrp, Yq, b1, W2, hw);
    k_l2        <<<NN / 4,    256, 0, stream>>>(offs, csrp, hw, b2, out);
}

// Round 18
// 171.775 us; speedup vs baseline: 1.3922x; 1.2680x over previous
//
#include <hip/hip_runtime.h>
#include <hip/hip_fp16.h>

#define NN 100000
#define NE 1600000
#define NEG_SLOPE 0.01f

#define NTL(x) __builtin_nontemporal_load(&(x))
typedef float fvec4 __attribute__((ext_vector_type(4)));
typedef float fvec2 __attribute__((ext_vector_type(2)));
typedef short bf16x8 __attribute__((ext_vector_type(8)));
typedef float f32x4 __attribute__((ext_vector_type(4)));

// Coarse buckets: 256 consecutive dst nodes each.
#define NB     391        // ceil(NN/256)
#define TILE   4096       // edges per binning workgroup
#define NTILES 391        // ceil(NE/TILE)
#define CAP    8192       // LDS stage capacity per bucket

// gemm1 (MFMA): 6250 16-row tiles, 2048 waves (512 blocks) grid-striding.
#define G1_BLOCKS 512
#define G1_WAVES  (G1_BLOCKS * 4)
#define G1_TILES  6250    // NN / 16 exactly

// ---------------------------------------------------------------------------
// Workspace layout (bytes) — total 26,008,384 B (< 26.4 MB proven).
//   offs  : (NN+1) int  @ 0          (400,004)
//   bcnt  : NB int      @ 400,384
//   boffs : (NB+1) int  @ 402,432
//   gcur  : NB int      @ 404,432
//   csrp  : NE int      @ 408,384    packed (src<<15 | w*32767), by dst, 6.4 MB
//   binned: NE int2     @ 6,808,384  bucket-grouped, 12.8 MB
//   Yq    : NN*64 fp8   @ 6,808,384  (ALIASES binned; binned dead before gemm1)
//   hw    : NN*32 fp16  @ 19,608,384 (6.4 MB)
#define OFF_BCNT  400384
#define OFF_BOFFS 402432
#define OFF_GCUR  404432
#define OFF_CSR   408384
#define OFF_YQ    6808384
#define OFF_HW    19608384

// ---------------------------------------------------------------------------
// A1: per-bucket edge counts (proven round 10).
__global__ __launch_bounds__(256) void k_bucketcnt(const int* __restrict__ dst,
                                                   int* __restrict__ bcnt)
{
    __shared__ int h[NB];
    int t = threadIdx.x;
    for (int i = t; i < NB; i += 256) h[i] = 0;
    __syncthreads();
    int base = blockIdx.x * TILE;
    for (int i = t; i < TILE; i += 256) {
        int e = base + i;
        if (e < NE) atomicAdd(&h[NTL(dst[e]) >> 8], 1);
    }
    __syncthreads();
    for (int i = t; i < NB; i += 256)
        if (h[i]) atomicAdd(&bcnt[i], h[i]);
}

// A2: exclusive scan of bucket counts (proven round 10).
__global__ __launch_bounds__(512) void k_bucketscan(const int* __restrict__ bcnt,
                                                    int* __restrict__ boffs,
                                                    int* __restrict__ gcur)
{
    __shared__ int lds[512];
    int t = threadIdx.x;
    int v = (t < NB) ? bcnt[t] : 0;
    lds[t] = v;
    __syncthreads();
    for (int off = 1; off < 512; off <<= 1) {
        int x = (t >= off) ? lds[t - off] : 0;
        __syncthreads();
        lds[t] += x;
        __syncthreads();
    }
    int excl = lds[t] - v;
    if (t < NB) { boffs[t] = excl; gcur[t] = excl; }
    if (t == NB - 1) boffs[NB] = lds[t];           // == NE
}

// A3: bin edges into bucket-grouped 'binned' (proven round 10).
__global__ __launch_bounds__(256) void k_binscatter(const int* __restrict__ dst,
                                                    const int* __restrict__ esrc,
                                                    const float* __restrict__ ew,
                                                    int* __restrict__ gcur,
                                                    int2* __restrict__ binned)
{
    __shared__ int   hist[NB];
    __shared__ int   cstart[NB];
    __shared__ int   ccur[NB];
    __shared__ int   gb[NB];
    __shared__ int   lds2[256];
    __shared__ int   sdst[TILE];
    __shared__ short sbuck[TILE];
    __shared__ int2  stage[TILE];

    int t = threadIdx.x;
    int base = blockIdx.x * TILE;
    int nvalid = NE - base; if (nvalid > TILE) nvalid = TILE;

    for (int i = t; i < NB; i += 256) hist[i] = 0;
    __syncthreads();
    for (int i = t; i < TILE; i += 256) {
        int e = base + i;
        int d = (e < NE) ? NTL(dst[e]) : -1;
        sdst[i] = d;
        if (d >= 0) atomicAdd(&hist[d >> 8], 1);
    }
    __syncthreads();

    int h0 = (2 * t     < NB) ? hist[2 * t]     : 0;
    int h1 = (2 * t + 1 < NB) ? hist[2 * t + 1] : 0;
    int ps = h0 + h1;
    lds2[t] = ps;
    __syncthreads();
    for (int off = 1; off < 256; off <<= 1) {
        int x = (t >= off) ? lds2[t - off] : 0;
        __syncthreads();
        lds2[t] += x;
        __syncthreads();
    }
    int excl = lds2[t] - ps;
    if (2 * t     < NB) { cstart[2 * t]     = excl;      ccur[2 * t]     = excl; }
    if (2 * t + 1 < NB) { cstart[2 * t + 1] = excl + h0; ccur[2 * t + 1] = excl + h0; }
    __syncthreads();

    for (int i = t; i < TILE; i += 256) {
        int d = sdst[i];
        if (d >= 0) {
            int e = base + i;
            int b = d >> 8;
            int pos = atomicAdd(&ccur[b], 1);
            stage[pos] = make_int2((NTL(esrc[e]) << 8) | (d & 255),
                                   __float_as_int(NTL(ew[e])));
            sbuck[pos] = (short)b;
        }
    }
    __syncthreads();

    for (int i = t; i < NB; i += 256)
        if (hist[i]) gb[i] = atomicAdd(&gcur[i], hist[i]);
    __syncthreads();
    for (int i = t; i < nvalid; i += 256) {
        int b = sbuck[i];
        binned[gb[b] + (i - cstart[b])] = stage[i];
    }
}

// B: per-bucket LDS counting sort -> csrp + offs (proven round 10).
__global__ __launch_bounds__(256) void k_bucketsort(const int2* __restrict__ binned,
                                                    const int* __restrict__ boffs,
                                                    int* __restrict__ offs,
                                                    int* __restrict__ csrp)
{
    __shared__ int nhist[256];
    __shared__ int nstart[256];
    __shared__ int ncur[256];
    __shared__ int lds[256];
    __shared__ int stage[CAP];

    int t = threadIdx.x, b = blockIdx.x;           // grid = NB
    int s0 = boffs[b], s1 = boffs[b + 1];
    int cnt = s1 - s0;

    nhist[t] = 0;
    __syncthreads();
    for (int i = t; i < cnt; i += 256)
        atomicAdd(&nhist[binned[s0 + i].x & 255], 1);
    __syncthreads();

    int v = nhist[t];
    lds[t] = v;
    __syncthreads();
    for (int off = 1; off < 256; off <<= 1) {
        int x = (t >= off) ? lds[t - off] : 0;
        __syncthreads();
        lds[t] += x;
        __syncthreads();
    }
    int excl = lds[t] - v;
    nstart[t] = excl;
    ncur[t] = excl;
    int node = b * 256 + t;
    if (node < NN) offs[node] = s0 + excl;
    if (b == NB - 1 && t == 0) offs[NN] = s1;      // == NE
    __syncthreads();

    for (int i = t; i < cnt; i += 256) {
        int2 r = binned[s0 + i];
        int dl = r.x & 255;
        unsigned src = ((unsigned)r.x) >> 8;
        float w = __int_as_float(r.y);
        unsigned wq = (unsigned)(w * 32767.0f + 0.5f);
        int pos = atomicAdd(&ncur[dl], 1);
        stage[pos] = (int)((src << 15) | wq);
    }
    __syncthreads();
    for (int i = t; i < cnt; i += 256)
        csrp[s0 + i] = stage[i];
}

// ---------------------------------------------------------------------------
// fp32 -> bf16 (round-nearest-even), bit manipulation, no bf16 header needed.
__device__ __forceinline__ short f2bf(float x)
{
    unsigned u = __float_as_uint(x);
    u += 0x7FFFu + ((u >> 16) & 1u);
    return (short)(u >> 16);
}

// ---------------------------------------------------------------------------
// Y = feats @ W1 -> fp8 e4m3, via MFMA (round 18: r14-r17 proved hipcc won't
// hold/pipeline the scalar form — matmul-shaped compute goes to matrix cores).
// Wave = one 16-row tile: 2 A-frags (feats fp32->bf16), 8 B-frags (W1, built
// once, loop-invariant), 8x mfma_f32_16x16x32_bf16, fp8 byte-store epilogue.
// Layouts: A row=lane&15, k=(lane>>4)*8+b; B col=lane&15 (symmetric);
// C/D col=lane&15, row=(lane>>4)*4+reg  [m89-verified].
__global__ __launch_bounds__(256) void k_gemm1(const float* __restrict__ feats,
                                               const float* __restrict__ W1,
                                               unsigned char* __restrict__ Yq)
{
    int lane = threadIdx.x & 63;
    int wid = (blockIdx.x * 256 + threadIdx.x) >> 6;   // 0..G1_WAVES-1
    int rc = lane & 15;          // A-row / B-col / D-col within tile
    int kg = lane >> 4;          // k-group (0..3)

    // B-frags [nt][kc]: W1[kc*32 + kg*8 + b][nt*16 + rc], built once.
    bf16x8 bfr[4][2];
    #pragma unroll
    for (int nt = 0; nt < 4; ++nt)
        #pragma unroll
        for (int kc = 0; kc < 2; ++kc) {
            int k0 = kc * 32 + kg * 8;
            #pragma unroll
            for (int b = 0; b < 8; ++b)
                bfr[nt][kc][b] = f2bf(W1[(k0 + b) * 64 + nt * 16 + rc]);
        }

    for (int t = wid; t < G1_TILES; t += G1_WAVES) {
        const float* ar = feats + (t * 16 + rc) * 64;
        bf16x8 af[2];
        #pragma unroll
        for (int kc = 0; kc < 2; ++kc) {
            const float4 v0 = *(const float4*)(ar + kc * 32 + kg * 8);
            const float4 v1 = *(const float4*)(ar + kc * 32 + kg * 8 + 4);
            af[kc][0] = f2bf(v0.x); af[kc][1] = f2bf(v0.y);
            af[kc][2] = f2bf(v0.z); af[kc][3] = f2bf(v0.w);
            af[kc][4] = f2bf(v1.x); af[kc][5] = f2bf(v1.y);
            af[kc][6] = f2bf(v1.z); af[kc][7] = f2bf(v1.w);
        }
        #pragma unroll
        for (int nt = 0; nt < 4; ++nt) {
            f32x4 acc = {0.f, 0.f, 0.f, 0.f};
            acc = __builtin_amdgcn_mfma_f32_16x16x32_bf16(af[0], bfr[nt][0], acc, 0, 0, 0);
            acc = __builtin_amdgcn_mfma_f32_16x16x32_bf16(af[1], bfr[nt][1], acc, 0, 0, 0);
            #pragma unroll
            for (int r = 0; r < 4; ++r) {
                int orow = t * 16 + kg * 4 + r;            // D row
                int b8 = __builtin_amdgcn_cvt_pk_fp8_f32(acc[r], acc[r], 0, false) & 0xFF;
                Yq[orow * 64 + nt * 16 + rc] = (unsigned char)b8;
            }
        }
    }
}

#define WDEC(c) ((float)((c) & 0x7fffu) * (1.0f / 32767.0f))

// ---------------------------------------------------------------------------
// Layer 1 (proven round 14): 4 edge-slots x 16 lanes x 4B fp8 gather; 8-shfl
// reduction; W2 in 32 VGPRs; h staged via 1 KB per-wave LDS.
__global__ __launch_bounds__(256) void k_l1(const int* __restrict__ offs,
                                            const int* __restrict__ csrp,
                                            const unsigned char* __restrict__ Yq,
                                            const float* __restrict__ b1,
                                            const float* __restrict__ W2,
                                            __half* __restrict__ hw)
{
    __shared__ __align__(16) float sh[4][64];      // per-wave h staging
    int tid = threadIdx.x;
    int lane = tid & 63;
    int wv = tid >> 6;
    int n = blockIdx.x * 4 + wv;                   // grid exact = NN waves
    int half = lane >> 5, c = lane & 31;

    float w2r[32];
    #pragma unroll
    for (int kk = 0; kk < 32; ++kk)
        w2r[kk] = W2[(half * 32 + kk) * 32 + c];

    int sub = lane >> 4;          // edge slot 0..3
    int e4  = lane & 15;          // col quad: cols [4*e4, 4*e4+4)
    const float4 bq = *(const float4*)(b1 + (e4 << 2));

    int start = offs[n], end = offs[n + 1];
    float a0 = 0.f, a1 = 0.f, a2 = 0.f, a3 = 0.f;
    for (int base = start; base < end; base += 64) {
        int m = end - base; if (m > 64) m = 64;
        int ed = (lane < m) ? NTL(csrp[base + lane]) : 0;   // pad: s=0, w=0
        int iters = (m + 3) >> 2;
        for (int i = 0; i < iters; ++i) {
            unsigned cc = (unsigned)__shfl(ed, (i << 2) + sub, 64);
            unsigned w8 = *(const unsigned*)(Yq + (cc >> 15) * 64 + (e4 << 2));
            float w = WDEC(cc);
            fvec2 lo = __builtin_amdgcn_cvt_pk_f32_fp8((int)w8, false);
            fvec2 hi = __builtin_amdgcn_cvt_pk_f32_fp8((int)w8, true);
            a0 = fmaf(w, lo.x, a0); a1 = fmaf(w, lo.y, a1);
            a2 = fmaf(w, hi.x, a2); a3 = fmaf(w, hi.y, a3);
        }
    }
    a0 += __shfl_xor(a0, 16, 64); a1 += __shfl_xor(a1, 16, 64);
    a2 += __shfl_xor(a2, 16, 64); a3 += __shfl_xor(a3, 16, 64);
    a0 += __shfl_xor(a0, 32, 64); a1 += __shfl_xor(a1, 32, 64);
    a2 += __shfl_xor(a2, 32, 64); a3 += __shfl_xor(a3, 32, 64);

    float h0 = a0 + bq.x, h1 = a1 + bq.y, h2 = a2 + bq.z, h3 = a3 + bq.w;
    h0 = h0 >= 0.f ? h0 : NEG_SLOPE * h0;  h1 = h1 >= 0.f ? h1 : NEG_SLOPE * h1;
    h2 = h2 >= 0.f ? h2 : NEG_SLOPE * h2;  h3 = h3 >= 0.f ? h3 : NEG_SLOPE * h3;

    if (sub == 0)
        *(float4*)&sh[wv][e4 << 2] = make_float4(h0, h1, h2, h3);
    __builtin_amdgcn_wave_barrier();               // keep write before reads

    float p = 0.f;
    #pragma unroll
    for (int q = 0; q < 8; ++q) {                  // broadcast reads, no conflicts
        float4 hv = *(const float4*)&sh[wv][(half << 5) + (q << 2)];
        p = fmaf(hv.x, w2r[4 * q + 0], p);
        p = fmaf(hv.y, w2r[4 * q + 1], p);
        p = fmaf(hv.z, w2r[4 * q + 2], p);
        p = fmaf(hv.w, w2r[4 * q + 3], p);
    }
    p += __shfl_xor(p, 32, 64);
    if (lane < 32) hw[n * 32 + lane] = __float2half(p);
}

// ---------------------------------------------------------------------------
// Layer 2 (proven round 14): 8 edge-slots x 8 lanes x 8B fp16; 12-shfl RED.
__global__ __launch_bounds__(256) void k_l2(const int* __restrict__ offs,
                                            const int* __restrict__ csrp,
                                            const __half* __restrict__ hw,
                                            const float* __restrict__ b2,
                                            float* __restrict__ out)
{
    int tid = threadIdx.x;
    int lane = tid & 63;
    int n = blockIdx.x * 4 + (tid >> 6);           // grid exact = NN waves
    int sub = lane >> 3;          // edge slot 0..7
    int e4  = lane & 7;           // col quad: cols [4*e4, 4*e4+4)
    const float4 bq = *(const float4*)(b2 + (e4 << 2));

    int start = offs[n], end = offs[n + 1];
    float a0 = 0.f, a1 = 0.f, a2 = 0.f, a3 = 0.f;
    for (int base = start; base < end; base += 64) {
        int m = end - base; if (m > 64) m = 64;
        int ed = (lane < m) ? NTL(csrp[base + lane]) : 0;   // pad: s=0, w=0
        int iters = (m + 7) >> 3;
        for (int i = 0; i < iters; ++i) {
            unsigned cc = (unsigned)__shfl(ed, (i << 3) + sub, 64);
            int2 raw = *(const int2*)(hw + (cc >> 15) * 32 + (e4 << 2));
            float w = WDEC(cc);
            float2 f0 = __half22float2(((const __half2*)&raw)[0]);
            float2 f1 = __half22float2(((const __half2*)&raw)[1]);
            a0 = fmaf(w, f0.x, a0); a1 = fmaf(w, f0.y, a1);
            a2 = fmaf(w, f1.x, a2); a3 = fmaf(w, f1.y, a3);
        }
    }
    a0 += __shfl_xor(a0,  8, 64); a1 += __shfl_xor(a1,  8, 64);
    a2 += __shfl_xor(a2,  8, 64); a3 += __shfl_xor(a3,  8, 64);
    a0 += __shfl_xor(a0, 16, 64); a1 += __shfl_xor(a1, 16, 64);
    a2 += __shfl_xor(a2, 16, 64); a3 += __shfl_xor(a3, 16, 64);
    a0 += __shfl_xor(a0, 32, 64); a1 += __shfl_xor(a1, 32, 64);
    a2 += __shfl_xor(a2, 32, 64); a3 += __shfl_xor(a3, 32, 64);

    if (sub == 0) {
        fvec4 o = { a0 + bq.x, a1 + bq.y, a2 + bq.z, a3 + bq.w };
        __builtin_nontemporal_store(o, (fvec4*)(out + n * 32 + (e4 << 2)));
    }
}

// ---------------------------------------------------------------------------
extern "C" void kernel_launch(void* const* d_in, const int* in_sizes, int n_in,
                              void* d_out, int out_size, void* d_ws, size_t ws_size,
                              hipStream_t stream)
{
    const float* feats = (const float*)d_in[0];
    const int*   esrc  = (const int*)d_in[1];
    const int*   edst  = (const int*)d_in[2];
    const float* ew    = (const float*)d_in[3];
    const float* W1    = (const float*)d_in[4];
    const float* b1    = (const float*)d_in[5];
    const float* W2    = (const float*)d_in[6];
    const float* b2    = (const float*)d_in[7];
    float* out = (float*)d_out;

    char*          ws     = (char*)d_ws;
    int*           offs   = (int*)ws;
    int*           bcnt   = (int*)(ws + OFF_BCNT);
    int*           boffs  = (int*)(ws + OFF_BOFFS);
    int*           gcur   = (int*)(ws + OFF_GCUR);
    int*           csrp   = (int*)(ws + OFF_CSR);
    int2*          binned = (int2*)(ws + OFF_YQ);  // aliases Yq; dead before gemm1
    unsigned char* Yq     = (unsigned char*)(ws + OFF_YQ);
    __half*        hw     = (__half*)(ws + OFF_HW);

    (void)hipMemsetAsync(bcnt, 0, NB * sizeof(int), stream);

    k_bucketcnt <<<NTILES,    256, 0, stream>>>(edst, bcnt);
    k_bucketscan<<<1,         512, 0, stream>>>(bcnt, boffs, gcur);
    k_binscatter<<<NTILES,    256, 0, stream>>>(edst, esrc, ew, gcur, binned);
    k_bucketsort<<<NB,        256, 0, stream>>>(binned, boffs, offs, csrp);
    k_gemm1     <<<G1_BLOCKS, 256, 0, stream>>>(feats, W1, Yq);
    k_l1        <<<NN / 4,    256, 0, stream>>>(offs, csrp, Yq, b1, W2, hw);
    k_l2        <<<NN / 4,    256, 0, stream>>>(offs, csrp, hw, b2, out);
}

// Round 19
// 150.509 us; speedup vs baseline: 1.5889x; 1.1413x over previous
//
#include <hip/hip_runtime.h>
#include <hip/hip_fp16.h>

#define NN 100000
#define NE 1600000
#define NEG_SLOPE 0.01f

#define NTL(x) __builtin_nontemporal_load(&(x))
typedef float fvec4 __attribute__((ext_vector_type(4)));
typedef float fvec2 __attribute__((ext_vector_type(2)));
typedef short bf16x8 __attribute__((ext_vector_type(8)));
typedef float f32x4 __attribute__((ext_vector_type(4)));

// Coarse buckets: 256 consecutive dst nodes each.
#define NB     391        // ceil(NN/256)
#define TILE   4096       // edges per binning workgroup
#define NTILES 391        // ceil(NE/TILE)
#define CAP    8192       // LDS stage capacity per bucket

// gemm1 (MFMA): 6250 16-row tiles, 2048 waves (512 blocks) grid-striding.
#define G1_BLOCKS 512
#define G1_WAVES  (G1_BLOCKS * 4)
#define G1_TILES  6250    // NN / 16 exactly

// ---------------------------------------------------------------------------
// Workspace layout (bytes) — total 26,008,384 B (< 26.4 MB proven).
//   offs  : (NN+1) int  @ 0          (400,004)
//   bcnt  : NB int      @ 400,384
//   boffs : (NB+1) int  @ 402,432
//   gcur  : NB int      @ 404,432
//   csrp  : NE int      @ 408,384    packed (src<<15 | w*32767), by dst, 6.4 MB
//   binned: NE int2     @ 6,808,384  bucket-grouped, 12.8 MB
//   Yq    : NN*64 fp8   @ 6,808,384  (ALIASES binned; binned dead before gemm1)
//   hw    : NN*32 fp16  @ 19,608,384 (6.4 MB)
#define OFF_BCNT  400384
#define OFF_BOFFS 402432
#define OFF_GCUR  404432
#define OFF_CSR   408384
#define OFF_YQ    6808384
#define OFF_HW    19608384

// ---------------------------------------------------------------------------
// A1: per-bucket edge counts (proven round 10).
__global__ __launch_bounds__(256) void k_bucketcnt(const int* __restrict__ dst,
                                                   int* __restrict__ bcnt)
{
    __shared__ int h[NB];
    int t = threadIdx.x;
    for (int i = t; i < NB; i += 256) h[i] = 0;
    __syncthreads();
    int base = blockIdx.x * TILE;
    for (int i = t; i < TILE; i += 256) {
        int e = base + i;
        if (e < NE) atomicAdd(&h[NTL(dst[e]) >> 8], 1);
    }
    __syncthreads();
    for (int i = t; i < NB; i += 256)
        if (h[i]) atomicAdd(&bcnt[i], h[i]);
}

// A2: exclusive scan of bucket counts (proven round 10).
__global__ __launch_bounds__(512) void k_bucketscan(const int* __restrict__ bcnt,
                                                    int* __restrict__ boffs,
                                                    int* __restrict__ gcur)
{
    __shared__ int lds[512];
    int t = threadIdx.x;
    int v = (t < NB) ? bcnt[t] : 0;
    lds[t] = v;
    __syncthreads();
    for (int off = 1; off < 512; off <<= 1) {
        int x = (t >= off) ? lds[t - off] : 0;
        __syncthreads();
        lds[t] += x;
        __syncthreads();
    }
    int excl = lds[t] - v;
    if (t < NB) { boffs[t] = excl; gcur[t] = excl; }
    if (t == NB - 1) boffs[NB] = lds[t];           // == NE
}

// A3: bin edges into bucket-grouped 'binned' (proven round 10).
__global__ __launch_bounds__(256) void k_binscatter(const int* __restrict__ dst,
                                                    const int* __restrict__ esrc,
                                                    const float* __restrict__ ew,
                                                    int* __restrict__ gcur,
                                                    int2* __restrict__ binned)
{
    __shared__ int   hist[NB];
    __shared__ int   cstart[NB];
    __shared__ int   ccur[NB];
    __shared__ int   gb[NB];
    __shared__ int   lds2[256];
    __shared__ int   sdst[TILE];
    __shared__ short sbuck[TILE];
    __shared__ int2  stage[TILE];

    int t = threadIdx.x;
    int base = blockIdx.x * TILE;
    int nvalid = NE - base; if (nvalid > TILE) nvalid = TILE;

    for (int i = t; i < NB; i += 256) hist[i] = 0;
    __syncthreads();
    for (int i = t; i < TILE; i += 256) {
        int e = base + i;
        int d = (e < NE) ? NTL(dst[e]) : -1;
        sdst[i] = d;
        if (d >= 0) atomicAdd(&hist[d >> 8], 1);
    }
    __syncthreads();

    int h0 = (2 * t     < NB) ? hist[2 * t]     : 0;
    int h1 = (2 * t + 1 < NB) ? hist[2 * t + 1] : 0;
    int ps = h0 + h1;
    lds2[t] = ps;
    __syncthreads();
    for (int off = 1; off < 256; off <<= 1) {
        int x = (t >= off) ? lds2[t - off] : 0;
        __syncthreads();
        lds2[t] += x;
        __syncthreads();
    }
    int excl = lds2[t] - ps;
    if (2 * t     < NB) { cstart[2 * t]     = excl;      ccur[2 * t]     = excl; }
    if (2 * t + 1 < NB) { cstart[2 * t + 1] = excl + h0; ccur[2 * t + 1] = excl + h0; }
    __syncthreads();

    for (int i = t; i < TILE; i += 256) {
        int d = sdst[i];
        if (d >= 0) {
            int e = base + i;
            int b = d >> 8;
            int pos = atomicAdd(&ccur[b], 1);
            stage[pos] = make_int2((NTL(esrc[e]) << 8) | (d & 255),
                                   __float_as_int(NTL(ew[e])));
            sbuck[pos] = (short)b;
        }
    }
    __syncthreads();

    for (int i = t; i < NB; i += 256)
        if (hist[i]) gb[i] = atomicAdd(&gcur[i], hist[i]);
    __syncthreads();
    for (int i = t; i < nvalid; i += 256) {
        int b = sbuck[i];
        binned[gb[b] + (i - cstart[b])] = stage[i];
    }
}

// B: per-bucket LDS counting sort -> csrp + offs (proven round 10).
__global__ __launch_bounds__(256) void k_bucketsort(const int2* __restrict__ binned,
                                                    const int* __restrict__ boffs,
                                                    int* __restrict__ offs,
                                                    int* __restrict__ csrp)
{
    __shared__ int nhist[256];
    __shared__ int nstart[256];
    __shared__ int ncur[256];
    __shared__ int lds[256];
    __shared__ int stage[CAP];

    int t = threadIdx.x, b = blockIdx.x;           // grid = NB
    int s0 = boffs[b], s1 = boffs[b + 1];
    int cnt = s1 - s0;

    nhist[t] = 0;
    __syncthreads();
    for (int i = t; i < cnt; i += 256)
        atomicAdd(&nhist[binned[s0 + i].x & 255], 1);
    __syncthreads();

    int v = nhist[t];
    lds[t] = v;
    __syncthreads();
    for (int off = 1; off < 256; off <<= 1) {
        int x = (t >= off) ? lds[t - off] : 0;
        __syncthreads();
        lds[t] += x;
        __syncthreads();
    }
    int excl = lds[t] - v;
    nstart[t] = excl;
    ncur[t] = excl;
    int node = b * 256 + t;
    if (node < NN) offs[node] = s0 + excl;
    if (b == NB - 1 && t == 0) offs[NN] = s1;      // == NE
    __syncthreads();

    for (int i = t; i < cnt; i += 256) {
        int2 r = binned[s0 + i];
        int dl = r.x & 255;
        unsigned src = ((unsigned)r.x) >> 8;
        float w = __int_as_float(r.y);
        unsigned wq = (unsigned)(w * 32767.0f + 0.5f);
        int pos = atomicAdd(&ncur[dl], 1);
        stage[pos] = (int)((src << 15) | wq);
    }
    __syncthreads();
    for (int i = t; i < cnt; i += 256)
        csrp[s0 + i] = stage[i];
}

// ---------------------------------------------------------------------------
// fp32 -> bf16 (round-nearest-even).
__device__ __forceinline__ short f2bf(float x)
{
    unsigned u = __float_as_uint(x);
    u += 0x7FFFu + ((u >> 16) & 1u);
    return (short)(u >> 16);
}

// ---------------------------------------------------------------------------
// Y = feats @ W1 -> fp8 e4m3, via MFMA (proven round 18).
__global__ __launch_bounds__(256) void k_gemm1(const float* __restrict__ feats,
                                               const float* __restrict__ W1,
                                               unsigned char* __restrict__ Yq)
{
    int lane = threadIdx.x & 63;
    int wid = (blockIdx.x * 256 + threadIdx.x) >> 6;   // 0..G1_WAVES-1
    int rc = lane & 15;          // A-row / B-col / D-col within tile
    int kg = lane >> 4;          // k-group (0..3)

    bf16x8 bfr[4][2];
    #pragma unroll
    for (int nt = 0; nt < 4; ++nt)
        #pragma unroll
        for (int kc = 0; kc < 2; ++kc) {
            int k0 = kc * 32 + kg * 8;
            #pragma unroll
            for (int b = 0; b < 8; ++b)
                bfr[nt][kc][b] = f2bf(W1[(k0 + b) * 64 + nt * 16 + rc]);
        }

    for (int t = wid; t < G1_TILES; t += G1_WAVES) {
        const float* ar = feats + (t * 16 + rc) * 64;
        bf16x8 af[2];
        #pragma unroll
        for (int kc = 0; kc < 2; ++kc) {
            const float4 v0 = *(const float4*)(ar + kc * 32 + kg * 8);
            const float4 v1 = *(const float4*)(ar + kc * 32 + kg * 8 + 4);
            af[kc][0] = f2bf(v0.x); af[kc][1] = f2bf(v0.y);
            af[kc][2] = f2bf(v0.z); af[kc][3] = f2bf(v0.w);
            af[kc][4] = f2bf(v1.x); af[kc][5] = f2bf(v1.y);
            af[kc][6] = f2bf(v1.z); af[kc][7] = f2bf(v1.w);
        }
        #pragma unroll
        for (int nt = 0; nt < 4; ++nt) {
            f32x4 acc = {0.f, 0.f, 0.f, 0.f};
            acc = __builtin_amdgcn_mfma_f32_16x16x32_bf16(af[0], bfr[nt][0], acc, 0, 0, 0);
            acc = __builtin_amdgcn_mfma_f32_16x16x32_bf16(af[1], bfr[nt][1], acc, 0, 0, 0);
            #pragma unroll
            for (int r = 0; r < 4; ++r) {
                int orow = t * 16 + kg * 4 + r;            // D row
                int b8 = __builtin_amdgcn_cvt_pk_fp8_f32(acc[r], acc[r], 0, false) & 0xFF;
                Yq[orow * 64 + nt * 16 + rc] = (unsigned char)b8;
            }
        }
    }
}

#define WDEC(c) ((float)((c) & 0x7fffu) * (1.0f / 32767.0f))

// ---------------------------------------------------------------------------
// Layer 1 (round 19: TWO nodes per wave — doubles gather loads in flight;
// r18 profile: VALU 47%, rest latency). Per node: 4 edge-slots x 16 lanes x
// 4B fp8; 8-shfl reduce; W2-VGPR MLP via 1KB LDS stage.
__global__ __launch_bounds__(256) void k_l1(const int* __restrict__ offs,
                                            const int* __restrict__ csrp,
                                            const unsigned char* __restrict__ Yq,
                                            const float* __restrict__ b1,
                                            const float* __restrict__ W2,
                                            __half* __restrict__ hw)
{
    __shared__ __align__(16) float sh[4][2][64];   // per-wave, per-node h stage
    int tid = threadIdx.x;
    int lane = tid & 63;
    int wv = tid >> 6;
    int wid = blockIdx.x * 4 + wv;                 // grid exact = NN/2 waves
    int nA = wid * 2, nB = nA + 1;
    int half = lane >> 5, c = lane & 31;

    float w2r[32];
    #pragma unroll
    for (int kk = 0; kk < 32; ++kk)
        w2r[kk] = W2[(half * 32 + kk) * 32 + c];

    int sub = lane >> 4;          // edge slot 0..3
    int e4  = lane & 15;          // col quad: cols [4*e4, 4*e4+4)
    const float4 bq = *(const float4*)(b1 + (e4 << 2));

    int sA = offs[nA], eA = offs[nA + 1];
    int sB = offs[nB], eB = offs[nB + 1];

    float a0=0.f,a1=0.f,a2=0.f,a3=0.f;             // node A
    float g0=0.f,g1=0.f,g2=0.f,g3=0.f;             // node B
    for (int bA = sA, bB = sB; bA < eA || bB < eB; bA += 64, bB += 64) {
        int mA = eA - bA; mA = mA < 0 ? 0 : (mA > 64 ? 64 : mA);
        int mB = eB - bB; mB = mB < 0 ? 0 : (mB > 64 ? 64 : mB);
        int edA = (lane < mA) ? NTL(csrp[bA + lane]) : 0;   // pad: s=0, w=0
        int edB = (lane < mB) ? NTL(csrp[bB + lane]) : 0;
        int itA = (mA + 3) >> 2, itB = (mB + 3) >> 2;
        int it = itA > itB ? itA : itB;
        for (int i = 0; i < it; ++i) {
            unsigned cA = (unsigned)__shfl(edA, (i << 2) + sub, 64);
            unsigned cB = (unsigned)__shfl(edB, (i << 2) + sub, 64);
            unsigned wA8 = *(const unsigned*)(Yq + (cA >> 15) * 64 + (e4 << 2));
            unsigned wB8 = *(const unsigned*)(Yq + (cB >> 15) * 64 + (e4 << 2));
            float wA = WDEC(cA), wB = WDEC(cB);
            fvec2 lo, hi;
            lo = __builtin_amdgcn_cvt_pk_f32_fp8((int)wA8, false);
            hi = __builtin_amdgcn_cvt_pk_f32_fp8((int)wA8, true);
            a0 = fmaf(wA, lo.x, a0); a1 = fmaf(wA, lo.y, a1);
            a2 = fmaf(wA, hi.x, a2); a3 = fmaf(wA, hi.y, a3);
            lo = __builtin_amdgcn_cvt_pk_f32_fp8((int)wB8, false);
            hi = __builtin_amdgcn_cvt_pk_f32_fp8((int)wB8, true);
            g0 = fmaf(wB, lo.x, g0); g1 = fmaf(wB, lo.y, g1);
            g2 = fmaf(wB, hi.x, g2); g3 = fmaf(wB, hi.y, g3);
        }
    }
    a0 += __shfl_xor(a0, 16, 64); a1 += __shfl_xor(a1, 16, 64);
    a2 += __shfl_xor(a2, 16, 64); a3 += __shfl_xor(a3, 16, 64);
    a0 += __shfl_xor(a0, 32, 64); a1 += __shfl_xor(a1, 32, 64);
    a2 += __shfl_xor(a2, 32, 64); a3 += __shfl_xor(a3, 32, 64);
    g0 += __shfl_xor(g0, 16, 64); g1 += __shfl_xor(g1, 16, 64);
    g2 += __shfl_xor(g2, 16, 64); g3 += __shfl_xor(g3, 16, 64);
    g0 += __shfl_xor(g0, 32, 64); g1 += __shfl_xor(g1, 32, 64);
    g2 += __shfl_xor(g2, 32, 64); g3 += __shfl_xor(g3, 32, 64);

    float hA0 = a0 + bq.x, hA1 = a1 + bq.y, hA2 = a2 + bq.z, hA3 = a3 + bq.w;
    float hB0 = g0 + bq.x, hB1 = g1 + bq.y, hB2 = g2 + bq.z, hB3 = g3 + bq.w;
    hA0 = hA0>=0.f ? hA0 : NEG_SLOPE*hA0;  hA1 = hA1>=0.f ? hA1 : NEG_SLOPE*hA1;
    hA2 = hA2>=0.f ? hA2 : NEG_SLOPE*hA2;  hA3 = hA3>=0.f ? hA3 : NEG_SLOPE*hA3;
    hB0 = hB0>=0.f ? hB0 : NEG_SLOPE*hB0;  hB1 = hB1>=0.f ? hB1 : NEG_SLOPE*hB1;
    hB2 = hB2>=0.f ? hB2 : NEG_SLOPE*hB2;  hB3 = hB3>=0.f ? hB3 : NEG_SLOPE*hB3;

    if (sub == 0) {
        *(float4*)&sh[wv][0][e4 << 2] = make_float4(hA0, hA1, hA2, hA3);
        *(float4*)&sh[wv][1][e4 << 2] = make_float4(hB0, hB1, hB2, hB3);
    }
    __builtin_amdgcn_wave_barrier();               // keep writes before reads

    float pA = 0.f, pB = 0.f;
    #pragma unroll
    for (int q = 0; q < 8; ++q) {                  // broadcast reads
        float4 hvA = *(const float4*)&sh[wv][0][(half << 5) + (q << 2)];
        float4 hvB = *(const float4*)&sh[wv][1][(half << 5) + (q << 2)];
        pA = fmaf(hvA.x, w2r[4*q+0], pA); pB = fmaf(hvB.x, w2r[4*q+0], pB);
        pA = fmaf(hvA.y, w2r[4*q+1], pA); pB = fmaf(hvB.y, w2r[4*q+1], pB);
        pA = fmaf(hvA.z, w2r[4*q+2], pA); pB = fmaf(hvB.z, w2r[4*q+2], pB);
        pA = fmaf(hvA.w, w2r[4*q+3], pA); pB = fmaf(hvB.w, w2r[4*q+3], pB);
    }
    pA += __shfl_xor(pA, 32, 64);
    pB += __shfl_xor(pB, 32, 64);
    if (lane < 32) {
        hw[nA * 32 + lane] = __float2half(pA);
        hw[nB * 32 + lane] = __float2half(pB);
    }
}

// ---------------------------------------------------------------------------
// Layer 2 (round 19: TWO nodes per wave, same rationale). Per node: 8 edge-
// slots x 8 lanes x 8B fp16, 4 accumulators, 12-shfl RED; NT store.
__global__ __launch_bounds__(256) void k_l2(const int* __restrict__ offs,
                                            const int* __restrict__ csrp,
                                            const __half* __restrict__ hw,
                                            const float* __restrict__ b2,
                                            float* __restrict__ out)
{
    int tid = threadIdx.x;
    int lane = tid & 63;
    int wid = blockIdx.x * 4 + (tid >> 6);         // grid exact = NN/2 waves
    int nA = wid * 2, nB = nA + 1;
    int sub = lane >> 3;          // edge slot 0..7
    int e4  = lane & 7;           // col quad: cols [4*e4, 4*e4+4)
    const float4 bq = *(const float4*)(b2 + (e4 << 2));

    int sA = offs[nA], eA = offs[nA + 1];
    int sB = offs[nB], eB = offs[nB + 1];

    float a0=0.f,a1=0.f,a2=0.f,a3=0.f;             // node A
    float g0=0.f,g1=0.f,g2=0.f,g3=0.f;             // node B
    for (int bA = sA, bB = sB; bA < eA || bB < eB; bA += 64, bB += 64) {
        int mA = eA - bA; mA = mA < 0 ? 0 : (mA > 64 ? 64 : mA);
        int mB = eB - bB; mB = mB < 0 ? 0 : (mB > 64 ? 64 : mB);
        int edA = (lane < mA) ? NTL(csrp[bA + lane]) : 0;   // pad: s=0, w=0
        int edB = (lane < mB) ? NTL(csrp[bB + lane]) : 0;
        int itA = (mA + 7) >> 3, itB = (mB + 7) >> 3;
        int it = itA > itB ? itA : itB;
        for (int i = 0; i < it; ++i) {
            unsigned cA = (unsigned)__shfl(edA, (i << 3) + sub, 64);
            unsigned cB = (unsigned)__shfl(edB, (i << 3) + sub, 64);
            int2 rA = *(const int2*)(hw + (cA >> 15) * 32 + (e4 << 2));
            int2 rB = *(const int2*)(hw + (cB >> 15) * 32 + (e4 << 2));
            float wA = WDEC(cA), wB = WDEC(cB);
            float2 f0, f1;
            f0 = __half22float2(((const __half2*)&rA)[0]);
            f1 = __half22float2(((const __half2*)&rA)[1]);
            a0 = fmaf(wA, f0.x, a0); a1 = fmaf(wA, f0.y, a1);
            a2 = fmaf(wA, f1.x, a2); a3 = fmaf(wA, f1.y, a3);
            f0 = __half22float2(((const __half2*)&rB)[0]);
            f1 = __half22float2(((const __half2*)&rB)[1]);
            g0 = fmaf(wB, f0.x, g0); g1 = fmaf(wB, f0.y, g1);
            g2 = fmaf(wB, f1.x, g2); g3 = fmaf(wB, f1.y, g3);
        }
    }
    a0 += __shfl_xor(a0,  8, 64); a1 += __shfl_xor(a1,  8, 64);
    a2 += __shfl_xor(a2,  8, 64); a3 += __shfl_xor(a3,  8, 64);
    a0 += __shfl_xor(a0, 16, 64); a1 += __shfl_xor(a1, 16, 64);
    a2 += __shfl_xor(a2, 16, 64); a3 += __shfl_xor(a3, 16, 64);
    a0 += __shfl_xor(a0, 32, 64); a1 += __shfl_xor(a1, 32, 64);
    a2 += __shfl_xor(a2, 32, 64); a3 += __shfl_xor(a3, 32, 64);
    g0 += __shfl_xor(g0,  8, 64); g1 += __shfl_xor(g1,  8, 64);
    g2 += __shfl_xor(g2,  8, 64); g3 += __shfl_xor(g3,  8, 64);
    g0 += __shfl_xor(g0, 16, 64); g1 += __shfl_xor(g1, 16, 64);
    g2 += __shfl_xor(g2, 16, 64); g3 += __shfl_xor(g3, 16, 64);
    g0 += __shfl_xor(g0, 32, 64); g1 += __shfl_xor(g1, 32, 64);
    g2 += __shfl_xor(g2, 32, 64); g3 += __shfl_xor(g3, 32, 64);

    if (sub == 0) {
        fvec4 oA = { a0 + bq.x, a1 + bq.y, a2 + bq.z, a3 + bq.w };
        fvec4 oB = { g0 + bq.x, g1 + bq.y, g2 + bq.z, g3 + bq.w };
        __builtin_nontemporal_store(oA, (fvec4*)(out + nA * 32 + (e4 << 2)));
        __builtin_nontemporal_store(oB, (fvec4*)(out + nB * 32 + (e4 << 2)));
    }
}

// ---------------------------------------------------------------------------
extern "C" void kernel_launch(void* const* d_in, const int* in_sizes, int n_in,
                              void* d_out, int out_size, void* d_ws, size_t ws_size,
                              hipStream_t stream)
{
    const float* feats = (const float*)d_in[0];
    const int*   esrc  = (const int*)d_in[1];
    const int*   edst  = (const int*)d_in[2];
    const float* ew    = (const float*)d_in[3];
    const float* W1    = (const float*)d_in[4];
    const float* b1    = (const float*)d_in[5];
    const float* W2    = (const float*)d_in[6];
    const float* b2    = (const float*)d_in[7];
    float* out = (float*)d_out;

    char*          ws     = (char*)d_ws;
    int*           offs   = (int*)ws;
    int*           bcnt   = (int*)(ws + OFF_BCNT);
    int*           boffs  = (int*)(ws + OFF_BOFFS);
    int*           gcur   = (int*)(ws + OFF_GCUR);
    int*           csrp   = (int*)(ws + OFF_CSR);
    int2*          binned = (int2*)(ws + OFF_YQ);  // aliases Yq; dead before gemm1
    unsigned char* Yq     = (unsigned char*)(ws + OFF_YQ);
    __half*        hw     = (__half*)(ws + OFF_HW);

    (void)hipMemsetAsync(bcnt, 0, NB * sizeof(int), stream);

    k_bucketcnt <<<NTILES,    256, 0, stream>>>(edst, bcnt);
    k_bucketscan<<<1,         512, 0, stream>>>(bcnt, boffs, gcur);
    k_binscatter<<<NTILES,    256, 0, stream>>>(edst, esrc, ew, gcur, binned);
    k_bucketsort<<<NB,        256, 0, stream>>>(binned, boffs, offs, csrp);
    k_gemm1     <<<G1_BLOCKS, 256, 0, stream>>>(feats, W1, Yq);
    k_l1        <<<NN / 8,    256, 0, stream>>>(offs, csrp, Yq, b1, W2, hw);
    k_l2        <<<NN / 8,    256, 0, stream>>>(offs, csrp, hw, b2, out);
}

// Round 20
// 143.960 us; speedup vs baseline: 1.6612x; 1.0455x over previous
//
#include <hip/hip_runtime.h>
#include <hip/hip_fp16.h>

#define NN 100000
#define NE 1600000
#define NEG_SLOPE 0.01f

#define NTL(x) __builtin_nontemporal_load(&(x))
typedef float fvec4 __attribute__((ext_vector_type(4)));
typedef float fvec2 __attribute__((ext_vector_type(2)));
typedef short bf16x8 __attribute__((ext_vector_type(8)));
typedef float f32x4 __attribute__((ext_vector_type(4)));

// Coarse buckets: 256 consecutive dst nodes each.
#define NB     391        // ceil(NN/256)
#define TILE   4096       // edges per binning workgroup
#define NTILES 391        // ceil(NE/TILE)
#define CAP    8192       // LDS stage capacity per bucket

// gemm1 (MFMA): 6250 16-row tiles, 2048 waves (512 blocks) grid-striding.
#define G1_BLOCKS 512
#define G1_WAVES  (G1_BLOCKS * 4)
#define G1_TILES  6250    // NN / 16 exactly

// ---------------------------------------------------------------------------
// Workspace layout (bytes) — total 26,008,384 B (< 26.4 MB proven).
//   offs  : (NN+1) int  @ 0          (400,004)
//   bcnt  : NB int      @ 400,384
//   boffs : (NB+1) int  @ 402,432
//   gcur  : NB int      @ 404,432
//   csrp  : NE int      @ 408,384    packed (src<<15 | w*32767), by dst, 6.4 MB
//   binned: NE int2     @ 6,808,384  bucket-grouped, 12.8 MB
//   Yq    : NN*64 fp8   @ 6,808,384  (ALIASES binned; binned dead before gemm1)
//   hw    : NN*32 fp16  @ 19,608,384 (6.4 MB)
#define OFF_BCNT  400384
#define OFF_BOFFS 402432
#define OFF_GCUR  404432
#define OFF_CSR   408384
#define OFF_YQ    6808384
#define OFF_HW    19608384

// ---------------------------------------------------------------------------
// A1: per-bucket edge counts (proven round 10).
__global__ __launch_bounds__(256) void k_bucketcnt(const int* __restrict__ dst,
                                                   int* __restrict__ bcnt)
{
    __shared__ int h[NB];
    int t = threadIdx.x;
    for (int i = t; i < NB; i += 256) h[i] = 0;
    __syncthreads();
    int base = blockIdx.x * TILE;
    for (int i = t; i < TILE; i += 256) {
        int e = base + i;
        if (e < NE) atomicAdd(&h[NTL(dst[e]) >> 8], 1);
    }
    __syncthreads();
    for (int i = t; i < NB; i += 256)
        if (h[i]) atomicAdd(&bcnt[i], h[i]);
}

// A2: exclusive scan of bucket counts (proven round 10).
__global__ __launch_bounds__(512) void k_bucketscan(const int* __restrict__ bcnt,
                                                    int* __restrict__ boffs,
                                                    int* __restrict__ gcur)
{
    __shared__ int lds[512];
    int t = threadIdx.x;
    int v = (t < NB) ? bcnt[t] : 0;
    lds[t] = v;
    __syncthreads();
    for (int off = 1; off < 512; off <<= 1) {
        int x = (t >= off) ? lds[t - off] : 0;
        __syncthreads();
        lds[t] += x;
        __syncthreads();
    }
    int excl = lds[t] - v;
    if (t < NB) { boffs[t] = excl; gcur[t] = excl; }
    if (t == NB - 1) boffs[NB] = lds[t];           // == NE
}

// A3: bin edges into bucket-grouped 'binned' (proven round 10).
__global__ __launch_bounds__(256) void k_binscatter(const int* __restrict__ dst,
                                                    const int* __restrict__ esrc,
                                                    const float* __restrict__ ew,
                                                    int* __restrict__ gcur,
                                                    int2* __restrict__ binned)
{
    __shared__ int   hist[NB];
    __shared__ int   cstart[NB];
    __shared__ int   ccur[NB];
    __shared__ int   gb[NB];
    __shared__ int   lds2[256];
    __shared__ int   sdst[TILE];
    __shared__ short sbuck[TILE];
    __shared__ int2  stage[TILE];

    int t = threadIdx.x;
    int base = blockIdx.x * TILE;
    int nvalid = NE - base; if (nvalid > TILE) nvalid = TILE;

    for (int i = t; i < NB; i += 256) hist[i] = 0;
    __syncthreads();
    for (int i = t; i < TILE; i += 256) {
        int e = base + i;
        int d = (e < NE) ? NTL(dst[e]) : -1;
        sdst[i] = d;
        if (d >= 0) atomicAdd(&hist[d >> 8], 1);
    }
    __syncthreads();

    int h0 = (2 * t     < NB) ? hist[2 * t]     : 0;
    int h1 = (2 * t + 1 < NB) ? hist[2 * t + 1] : 0;
    int ps = h0 + h1;
    lds2[t] = ps;
    __syncthreads();
    for (int off = 1; off < 256; off <<= 1) {
        int x = (t >= off) ? lds2[t - off] : 0;
        __syncthreads();
        lds2[t] += x;
        __syncthreads();
    }
    int excl = lds2[t] - ps;
    if (2 * t     < NB) { cstart[2 * t]     = excl;      ccur[2 * t]     = excl; }
    if (2 * t + 1 < NB) { cstart[2 * t + 1] = excl + h0; ccur[2 * t + 1] = excl + h0; }
    __syncthreads();

    for (int i = t; i < TILE; i += 256) {
        int d = sdst[i];
        if (d >= 0) {
            int e = base + i;
            int b = d >> 8;
            int pos = atomicAdd(&ccur[b], 1);
            stage[pos] = make_int2((NTL(esrc[e]) << 8) | (d & 255),
                                   __float_as_int(NTL(ew[e])));
            sbuck[pos] = (short)b;
        }
    }
    __syncthreads();

    for (int i = t; i < NB; i += 256)
        if (hist[i]) gb[i] = atomicAdd(&gcur[i], hist[i]);
    __syncthreads();
    for (int i = t; i < nvalid; i += 256) {
        int b = sbuck[i];
        binned[gb[b] + (i - cstart[b])] = stage[i];
    }
}

// B: per-bucket LDS counting sort -> csrp + offs (proven round 10).
__global__ __launch_bounds__(256) void k_bucketsort(const int2* __restrict__ binned,
                                                    const int* __restrict__ boffs,
                                                    int* __restrict__ offs,
                                                    int* __restrict__ csrp)
{
    __shared__ int nhist[256];
    __shared__ int nstart[256];
    __shared__ int ncur[256];
    __shared__ int lds[256];
    __shared__ int stage[CAP];

    int t = threadIdx.x, b = blockIdx.x;           // grid = NB
    int s0 = boffs[b], s1 = boffs[b + 1];
    int cnt = s1 - s0;

    nhist[t] = 0;
    __syncthreads();
    for (int i = t; i < cnt; i += 256)
        atomicAdd(&nhist[binned[s0 + i].x & 255], 1);
    __syncthreads();

    int v = nhist[t];
    lds[t] = v;
    __syncthreads();
    for (int off = 1; off < 256; off <<= 1) {
        int x = (t >= off) ? lds[t - off] : 0;
        __syncthreads();
        lds[t] += x;
        __syncthreads();
    }
    int excl = lds[t] - v;
    nstart[t] = excl;
    ncur[t] = excl;
    int node = b * 256 + t;
    if (node < NN) offs[node] = s0 + excl;
    if (b == NB - 1 && t == 0) offs[NN] = s1;      // == NE
    __syncthreads();

    for (int i = t; i < cnt; i += 256) {
        int2 r = binned[s0 + i];
        int dl = r.x & 255;
        unsigned src = ((unsigned)r.x) >> 8;
        float w = __int_as_float(r.y);
        unsigned wq = (unsigned)(w * 32767.0f + 0.5f);
        int pos = atomicAdd(&ncur[dl], 1);
        stage[pos] = (int)((src << 15) | wq);
    }
    __syncthreads();
    for (int i = t; i < cnt; i += 256)
        csrp[s0 + i] = stage[i];
}

// ---------------------------------------------------------------------------
// fp32 -> bf16 (round-nearest-even).
__device__ __forceinline__ short f2bf(float x)
{
    unsigned u = __float_as_uint(x);
    u += 0x7FFFu + ((u >> 16) & 1u);
    return (short)(u >> 16);
}

// ---------------------------------------------------------------------------
// Y = feats @ W1 -> fp8 e4m3, via MFMA (proven round 18).
__global__ __launch_bounds__(256) void k_gemm1(const float* __restrict__ feats,
                                               const float* __restrict__ W1,
                                               unsigned char* __restrict__ Yq)
{
    int lane = threadIdx.x & 63;
    int wid = (blockIdx.x * 256 + threadIdx.x) >> 6;   // 0..G1_WAVES-1
    int rc = lane & 15;          // A-row / B-col / D-col within tile
    int kg = lane >> 4;          // k-group (0..3)

    bf16x8 bfr[4][2];
    #pragma unroll
    for (int nt = 0; nt < 4; ++nt)
        #pragma unroll
        for (int kc = 0; kc < 2; ++kc) {
            int k0 = kc * 32 + kg * 8;
            #pragma unroll
            for (int b = 0; b < 8; ++b)
                bfr[nt][kc][b] = f2bf(W1[(k0 + b) * 64 + nt * 16 + rc]);
        }

    for (int t = wid; t < G1_TILES; t += G1_WAVES) {
        const float* ar = feats + (t * 16 + rc) * 64;
        bf16x8 af[2];
        #pragma unroll
        for (int kc = 0; kc < 2; ++kc) {
            const float4 v0 = *(const float4*)(ar + kc * 32 + kg * 8);
            const float4 v1 = *(const float4*)(ar + kc * 32 + kg * 8 + 4);
            af[kc][0] = f2bf(v0.x); af[kc][1] = f2bf(v0.y);
            af[kc][2] = f2bf(v0.z); af[kc][3] = f2bf(v0.w);
            af[kc][4] = f2bf(v1.x); af[kc][5] = f2bf(v1.y);
            af[kc][6] = f2bf(v1.z); af[kc][7] = f2bf(v1.w);
        }
        #pragma unroll
        for (int nt = 0; nt < 4; ++nt) {
            f32x4 acc = {0.f, 0.f, 0.f, 0.f};
            acc = __builtin_amdgcn_mfma_f32_16x16x32_bf16(af[0], bfr[nt][0], acc, 0, 0, 0);
            acc = __builtin_amdgcn_mfma_f32_16x16x32_bf16(af[1], bfr[nt][1], acc, 0, 0, 0);
            #pragma unroll
            for (int r = 0; r < 4; ++r) {
                int orow = t * 16 + kg * 4 + r;            // D row
                int b8 = __builtin_amdgcn_cvt_pk_fp8_f32(acc[r], acc[r], 0, false) & 0xFF;
                Yq[orow * 64 + nt * 16 + rc] = (unsigned char)b8;
            }
        }
    }
}

#define WDEC(c) ((float)((c) & 0x7fffu) * (1.0f / 32767.0f))

// ---------------------------------------------------------------------------
// Layer 1 (round 20: FOUR nodes per wave — 4 gather streams in flight; r19
// showed VALU 50%, half still latency). Per node: 4 edge-slots x 16 lanes x
// 4B fp8; 8-shfl reduce; W2 MLP via LDS stage.
__global__ __launch_bounds__(256) void k_l1(const int* __restrict__ offs,
                                            const int* __restrict__ csrp,
                                            const unsigned char* __restrict__ Yq,
                                            const float* __restrict__ b1,
                                            const float* __restrict__ W2,
                                            __half* __restrict__ hw)
{
    __shared__ __align__(16) float sh[4][4][64];   // per-wave, per-node h stage
    int tid = threadIdx.x;
    int lane = tid & 63;
    int wv = tid >> 6;
    int wid = blockIdx.x * 4 + wv;                 // grid exact = NN/4 waves
    int n0 = wid * 4;
    int half = lane >> 5, c = lane & 31;

    float w2r[32];
    #pragma unroll
    for (int kk = 0; kk < 32; ++kk)
        w2r[kk] = W2[(half * 32 + kk) * 32 + c];

    int sub = lane >> 4;          // edge slot 0..3
    int e4  = lane & 15;          // col quad: cols [4*e4, 4*e4+4)
    const float4 bq = *(const float4*)(b1 + (e4 << 2));

    int sA = offs[n0],     eA = offs[n0 + 1];
    int sB = offs[n0 + 1], eB = offs[n0 + 2];
    int sC = offs[n0 + 2], eC = offs[n0 + 3];
    int sD = offs[n0 + 3], eD = offs[n0 + 4];

    float a0=0.f,a1=0.f,a2=0.f,a3=0.f;             // node A
    float g0=0.f,g1=0.f,g2=0.f,g3=0.f;             // node B
    float q0=0.f,q1=0.f,q2=0.f,q3=0.f;             // node C
    float r0=0.f,r1=0.f,r2=0.f,r3=0.f;             // node D
    for (int bA=sA, bB=sB, bC=sC, bD=sD;
         bA < eA || bB < eB || bC < eC || bD < eD;
         bA += 64, bB += 64, bC += 64, bD += 64) {
        int mA = eA-bA; mA = mA<0?0:(mA>64?64:mA);
        int mB = eB-bB; mB = mB<0?0:(mB>64?64:mB);
        int mC = eC-bC; mC = mC<0?0:(mC>64?64:mC);
        int mD = eD-bD; mD = mD<0?0:(mD>64?64:mD);
        int edA = (lane < mA) ? NTL(csrp[bA + lane]) : 0;   // pad: s=0, w=0
        int edB = (lane < mB) ? NTL(csrp[bB + lane]) : 0;
        int edC = (lane < mC) ? NTL(csrp[bC + lane]) : 0;
        int edD = (lane < mD) ? NTL(csrp[bD + lane]) : 0;
        int it = (mA+3)>>2;
        int t2 = (mB+3)>>2; if (t2 > it) it = t2;
        t2 = (mC+3)>>2; if (t2 > it) it = t2;
        t2 = (mD+3)>>2; if (t2 > it) it = t2;
        for (int i = 0; i < it; ++i) {
            int j = (i << 2) + sub;
            unsigned cA = (unsigned)__shfl(edA, j, 64);
            unsigned cB = (unsigned)__shfl(edB, j, 64);
            unsigned cC = (unsigned)__shfl(edC, j, 64);
            unsigned cD = (unsigned)__shfl(edD, j, 64);
            unsigned wA8 = *(const unsigned*)(Yq + (cA >> 15) * 64 + (e4 << 2));
            unsigned wB8 = *(const unsigned*)(Yq + (cB >> 15) * 64 + (e4 << 2));
            unsigned wC8 = *(const unsigned*)(Yq + (cC >> 15) * 64 + (e4 << 2));
            unsigned wD8 = *(const unsigned*)(Yq + (cD >> 15) * 64 + (e4 << 2));
            float wA = WDEC(cA), wB = WDEC(cB), wC = WDEC(cC), wD = WDEC(cD);
            fvec2 lo, hi;
            lo = __builtin_amdgcn_cvt_pk_f32_fp8((int)wA8, false);
            hi = __builtin_amdgcn_cvt_pk_f32_fp8((int)wA8, true);
            a0 = fmaf(wA, lo.x, a0); a1 = fmaf(wA, lo.y, a1);
            a2 = fmaf(wA, hi.x, a2); a3 = fmaf(wA, hi.y, a3);
            lo = __builtin_amdgcn_cvt_pk_f32_fp8((int)wB8, false);
            hi = __builtin_amdgcn_cvt_pk_f32_fp8((int)wB8, true);
            g0 = fmaf(wB, lo.x, g0); g1 = fmaf(wB, lo.y, g1);
            g2 = fmaf(wB, hi.x, g2); g3 = fmaf(wB, hi.y, g3);
            lo = __builtin_amdgcn_cvt_pk_f32_fp8((int)wC8, false);
            hi = __builtin_amdgcn_cvt_pk_f32_fp8((int)wC8, true);
            q0 = fmaf(wC, lo.x, q0); q1 = fmaf(wC, lo.y, q1);
            q2 = fmaf(wC, hi.x, q2); q3 = fmaf(wC, hi.y, q3);
            lo = __builtin_amdgcn_cvt_pk_f32_fp8((int)wD8, false);
            hi = __builtin_amdgcn_cvt_pk_f32_fp8((int)wD8, true);
            r0 = fmaf(wD, lo.x, r0); r1 = fmaf(wD, lo.y, r1);
            r2 = fmaf(wD, hi.x, r2); r3 = fmaf(wD, hi.y, r3);
        }
    }
    #define REDL1(x) x += __shfl_xor(x, 16, 64); x += __shfl_xor(x, 32, 64);
    REDL1(a0) REDL1(a1) REDL1(a2) REDL1(a3)
    REDL1(g0) REDL1(g1) REDL1(g2) REDL1(g3)
    REDL1(q0) REDL1(q1) REDL1(q2) REDL1(q3)
    REDL1(r0) REDL1(r1) REDL1(r2) REDL1(r3)

    #define LRELU(x) ((x) >= 0.f ? (x) : NEG_SLOPE * (x))
    if (sub == 0) {
        *(float4*)&sh[wv][0][e4 << 2] = make_float4(
            LRELU(a0 + bq.x), LRELU(a1 + bq.y), LRELU(a2 + bq.z), LRELU(a3 + bq.w));
        *(float4*)&sh[wv][1][e4 << 2] = make_float4(
            LRELU(g0 + bq.x), LRELU(g1 + bq.y), LRELU(g2 + bq.z), LRELU(g3 + bq.w));
        *(float4*)&sh[wv][2][e4 << 2] = make_float4(
            LRELU(q0 + bq.x), LRELU(q1 + bq.y), LRELU(q2 + bq.z), LRELU(q3 + bq.w));
        *(float4*)&sh[wv][3][e4 << 2] = make_float4(
            LRELU(r0 + bq.x), LRELU(r1 + bq.y), LRELU(r2 + bq.z), LRELU(r3 + bq.w));
    }
    __builtin_amdgcn_wave_barrier();               // keep writes before reads

    float pA = 0.f, pB = 0.f, pC = 0.f, pD = 0.f;
    #pragma unroll
    for (int q = 0; q < 8; ++q) {                  // broadcast reads
        float4 hvA = *(const float4*)&sh[wv][0][(half << 5) + (q << 2)];
        float4 hvB = *(const float4*)&sh[wv][1][(half << 5) + (q << 2)];
        float4 hvC = *(const float4*)&sh[wv][2][(half << 5) + (q << 2)];
        float4 hvD = *(const float4*)&sh[wv][3][(half << 5) + (q << 2)];
        pA = fmaf(hvA.x, w2r[4*q+0], pA); pB = fmaf(hvB.x, w2r[4*q+0], pB);
        pC = fmaf(hvC.x, w2r[4*q+0], pC); pD = fmaf(hvD.x, w2r[4*q+0], pD);
        pA = fmaf(hvA.y, w2r[4*q+1], pA); pB = fmaf(hvB.y, w2r[4*q+1], pB);
        pC = fmaf(hvC.y, w2r[4*q+1], pC); pD = fmaf(hvD.y, w2r[4*q+1], pD);
        pA = fmaf(hvA.z, w2r[4*q+2], pA); pB = fmaf(hvB.z, w2r[4*q+2], pB);
        pC = fmaf(hvC.z, w2r[4*q+2], pC); pD = fmaf(hvD.z, w2r[4*q+2], pD);
        pA = fmaf(hvA.w, w2r[4*q+3], pA); pB = fmaf(hvB.w, w2r[4*q+3], pB);
        pC = fmaf(hvC.w, w2r[4*q+3], pC); pD = fmaf(hvD.w, w2r[4*q+3], pD);
    }
    pA += __shfl_xor(pA, 32, 64);
    pB += __shfl_xor(pB, 32, 64);
    pC += __shfl_xor(pC, 32, 64);
    pD += __shfl_xor(pD, 32, 64);
    if (lane < 32) {
        hw[(n0 + 0) * 32 + lane] = __float2half(pA);
        hw[(n0 + 1) * 32 + lane] = __float2half(pB);
        hw[(n0 + 2) * 32 + lane] = __float2half(pC);
        hw[(n0 + 3) * 32 + lane] = __float2half(pD);
    }
}

// ---------------------------------------------------------------------------
// Layer 2 (round 20: FOUR nodes per wave). Per node: 8 edge-slots x 8 lanes x
// 8B fp16, 4 accumulators, 12-shfl RED; NT store.
__global__ __launch_bounds__(256) void k_l2(const int* __restrict__ offs,
                                            const int* __restrict__ csrp,
                                            const __half* __restrict__ hw,
                                            const float* __restrict__ b2,
                                            float* __restrict__ out)
{
    int tid = threadIdx.x;
    int lane = tid & 63;
    int wid = blockIdx.x * 4 + (tid >> 6);         // grid exact = NN/4 waves
    int n0 = wid * 4;
    int sub = lane >> 3;          // edge slot 0..7
    int e4  = lane & 7;           // col quad: cols [4*e4, 4*e4+4)
    const float4 bq = *(const float4*)(b2 + (e4 << 2));

    int sA = offs[n0],     eA = offs[n0 + 1];
    int sB = offs[n0 + 1], eB = offs[n0 + 2];
    int sC = offs[n0 + 2], eC = offs[n0 + 3];
    int sD = offs[n0 + 3], eD = offs[n0 + 4];

    float a0=0.f,a1=0.f,a2=0.f,a3=0.f;
    float g0=0.f,g1=0.f,g2=0.f,g3=0.f;
    float q0=0.f,q1=0.f,q2=0.f,q3=0.f;
    float r0=0.f,r1=0.f,r2=0.f,r3=0.f;
    for (int bA=sA, bB=sB, bC=sC, bD=sD;
         bA < eA || bB < eB || bC < eC || bD < eD;
         bA += 64, bB += 64, bC += 64, bD += 64) {
        int mA = eA-bA; mA = mA<0?0:(mA>64?64:mA);
        int mB = eB-bB; mB = mB<0?0:(mB>64?64:mB);
        int mC = eC-bC; mC = mC<0?0:(mC>64?64:mC);
        int mD = eD-bD; mD = mD<0?0:(mD>64?64:mD);
        int edA = (lane < mA) ? NTL(csrp[bA + lane]) : 0;   // pad: s=0, w=0
        int edB = (lane < mB) ? NTL(csrp[bB + lane]) : 0;
        int edC = (lane < mC) ? NTL(csrp[bC + lane]) : 0;
        int edD = (lane < mD) ? NTL(csrp[bD + lane]) : 0;
        int it = (mA+7)>>3;
        int t2 = (mB+7)>>3; if (t2 > it) it = t2;
        t2 = (mC+7)>>3; if (t2 > it) it = t2;
        t2 = (mD+7)>>3; if (t2 > it) it = t2;
        for (int i = 0; i < it; ++i) {
            int j = (i << 3) + sub;
            unsigned cA = (unsigned)__shfl(edA, j, 64);
            unsigned cB = (unsigned)__shfl(edB, j, 64);
            unsigned cC = (unsigned)__shfl(edC, j, 64);
            unsigned cD = (unsigned)__shfl(edD, j, 64);
            int2 rA = *(const int2*)(hw + (cA >> 15) * 32 + (e4 << 2));
            int2 rB = *(const int2*)(hw + (cB >> 15) * 32 + (e4 << 2));
            int2 rC = *(const int2*)(hw + (cC >> 15) * 32 + (e4 << 2));
            int2 rD = *(const int2*)(hw + (cD >> 15) * 32 + (e4 << 2));
            float wA = WDEC(cA), wB = WDEC(cB), wC = WDEC(cC), wD = WDEC(cD);
            float2 f0, f1;
            f0 = __half22float2(((const __half2*)&rA)[0]);
            f1 = __half22float2(((const __half2*)&rA)[1]);
            a0 = fmaf(wA, f0.x, a0); a1 = fmaf(wA, f0.y, a1);
            a2 = fmaf(wA, f1.x, a2); a3 = fmaf(wA, f1.y, a3);
            f0 = __half22float2(((const __half2*)&rB)[0]);
            f1 = __half22float2(((const __half2*)&rB)[1]);
            g0 = fmaf(wB, f0.x, g0); g1 = fmaf(wB, f0.y, g1);
            g2 = fmaf(wB, f1.x, g2); g3 = fmaf(wB, f1.y, g3);
            f0 = __half22float2(((const __half2*)&rC)[0]);
            f1 = __half22float2(((const __half2*)&rC)[1]);
            q0 = fmaf(wC, f0.x, q0); q1 = fmaf(wC, f0.y, q1);
            q2 = fmaf(wC, f1.x, q2); q3 = fmaf(wC, f1.y, q3);
            f0 = __half22float2(((const __half2*)&rD)[0]);
            f1 = __half22float2(((const __half2*)&rD)[1]);
            r0 = fmaf(wD, f0.x, r0); r1 = fmaf(wD, f0.y, r1);
            r2 = fmaf(wD, f1.x, r2); r3 = fmaf(wD, f1.y, r3);
        }
    }
    #define REDL2(x) x += __shfl_xor(x, 8, 64); x += __shfl_xor(x, 16, 64); \
                     x += __shfl_xor(x, 32, 64);
    REDL2(a0) REDL2(a1) REDL2(a2) REDL2(a3)
    REDL2(g0) REDL2(g1) REDL2(g2) REDL2(g3)
    REDL2(q0) REDL2(q1) REDL2(q2) REDL2(q3)
    REDL2(r0) REDL2(r1) REDL2(r2) REDL2(r3)

    if (sub == 0) {
        fvec4 oA = { a0 + bq.x, a1 + bq.y, a2 + bq.z, a3 + bq.w };
        fvec4 oB = { g0 + bq.x, g1 + bq.y, g2 + bq.z, g3 + bq.w };
        fvec4 oC = { q0 + bq.x, q1 + bq.y, q2 + bq.z, q3 + bq.w };
        fvec4 oD = { r0 + bq.x, r1 + bq.y, r2 + bq.z, r3 + bq.w };
        __builtin_nontemporal_store(oA, (fvec4*)(out + (n0+0) * 32 + (e4 << 2)));
        __builtin_nontemporal_store(oB, (fvec4*)(out + (n0+1) * 32 + (e4 << 2)));
        __builtin_nontemporal_store(oC, (fvec4*)(out + (n0+2) * 32 + (e4 << 2)));
        __builtin_nontemporal_store(oD, (fvec4*)(out + (n0+3) * 32 + (e4 << 2)));
    }
}

// ---------------------------------------------------------------------------
extern "C" void kernel_launch(void* const* d_in, const int* in_sizes, int n_in,
                              void* d_out, int out_size, void* d_ws, size_t ws_size,
                              hipStream_t stream)
{
    const float* feats = (const float*)d_in[0];
    const int*   esrc  = (const int*)d_in[1];
    const int*   edst  = (const int*)d_in[2];
    const float* ew    = (const float*)d_in[3];
    const float* W1    = (const float*)d_in[4];
    const float* b1    = (const float*)d_in[5];
    const float* W2    = (const float*)d_in[6];
    const float* b2    = (const float*)d_in[7];
    float* out = (float*)d_out;

    char*          ws     = (char*)d_ws;
    int*           offs   = (int*)ws;
    int*           bcnt   = (int*)(ws + OFF_BCNT);
    int*           boffs  = (int*)(ws + OFF_BOFFS);
    int*           gcur   = (int*)(ws + OFF_GCUR);
    int*           csrp   = (int*)(ws + OFF_CSR);
    int2*          binned = (int2*)(ws + OFF_YQ);  // aliases Yq; dead before gemm1
    unsigned char* Yq     = (unsigned char*)(ws + OFF_YQ);
    __half*        hw     = (__half*)(ws + OFF_HW);

    (void)hipMemsetAsync(bcnt, 0, NB * sizeof(int), stream);

    k_bucketcnt <<<NTILES,    256, 0, stream>>>(edst, bcnt);
    k_bucketscan<<<1,         512, 0, stream>>>(bcnt, boffs, gcur);
    k_binscatter<<<NTILES,    256, 0, stream>>>(edst, esrc, ew, gcur, binned);
    k_bucketsort<<<NB,        256, 0, stream>>>(binned, boffs, offs, csrp);
    k_gemm1     <<<G1_BLOCKS, 256, 0, stream>>>(feats, W1, Yq);
    k_l1        <<<NN / 16,   256, 0, stream>>>(offs, csrp, Yq, b1, W2, hw);
    k_l2        <<<NN / 16,   256, 0, stream>>>(offs, csrp, hw, b2, out);
}

// Round 21
// 140.741 us; speedup vs baseline: 1.6992x; 1.0229x over previous
//
#include <hip/hip_runtime.h>
#include <hip/hip_fp16.h>

#define NN 100000
#define NE 1600000
#define NEG_SLOPE 0.01f

#define NTL(x) __builtin_nontemporal_load(&(x))
typedef float fvec4 __attribute__((ext_vector_type(4)));
typedef float fvec2 __attribute__((ext_vector_type(2)));
typedef short bf16x8 __attribute__((ext_vector_type(8)));
typedef float f32x4 __attribute__((ext_vector_type(4)));

// Coarse buckets: 256 consecutive dst nodes each.
#define NB     391        // ceil(NN/256)
#define TILE   4096       // edges per binning workgroup
#define NTILES 391        // ceil(NE/TILE)
#define CAP    8192       // LDS stage capacity per bucket

// gemm1 (MFMA, fused into binscatter dispatch): 512 blocks = 2048 waves.
#define G1_BLOCKS 512
#define G1_WAVES  (G1_BLOCKS * 4)
#define G1_TILES  6250    // NN / 16 exactly

// ---------------------------------------------------------------------------
// Workspace layout (bytes) — total ~21.3 MB (< 26.4 MB proven). Round 21:
// binned split into key(int)+dl(uchar) so Yq gets its OWN region -> gemm1 can
// run concurrently with the CSR build (fused dispatch). hw aliases key (dead
// after bucketsort).
//   offs : (NN+1) int   @ 0            (400,004 -> pad 400,384)
//   csrp : NE int       @ 400,384      (6.4 MB)
//   key  : NE int       @ 6,808,384    (src<<15|wq; 6.4 MB; later hw)
//   dl   : NE uchar     @ 13,208,384   (1.6 MB)
//   Yq   : NN*64 fp8    @ 14,808,384   (6.4 MB, own region)
//   bcnt : NB int       @ 21,208,384
//   boffs: (NB+1) int   @ 21,210,432
//   gcur : NB int       @ 21,212,480
#define OFF_CSR   400384
#define OFF_KEY   6808384
#define OFF_DL    13208384
#define OFF_YQ    14808384
#define OFF_BCNT  21208384
#define OFF_BOFFS 21210432
#define OFF_GCUR  21212480
#define OFF_HW    OFF_KEY     // hw aliases key

// ---------------------------------------------------------------------------
// A1: per-bucket edge counts (proven round 10).
__global__ __launch_bounds__(256) void k_bucketcnt(const int* __restrict__ dst,
                                                   int* __restrict__ bcnt)
{
    __shared__ int h[NB];
    int t = threadIdx.x;
    for (int i = t; i < NB; i += 256) h[i] = 0;
    __syncthreads();
    int base = blockIdx.x * TILE;
    for (int i = t; i < TILE; i += 256) {
        int e = base + i;
        if (e < NE) atomicAdd(&h[NTL(dst[e]) >> 8], 1);
    }
    __syncthreads();
    for (int i = t; i < NB; i += 256)
        if (h[i]) atomicAdd(&bcnt[i], h[i]);
}

// A2: exclusive scan of bucket counts (proven round 10).
__global__ __launch_bounds__(512) void k_bucketscan(const int* __restrict__ bcnt,
                                                    int* __restrict__ boffs,
                                                    int* __restrict__ gcur)
{
    __shared__ int lds[512];
    int t = threadIdx.x;
    int v = (t < NB) ? bcnt[t] : 0;
    lds[t] = v;
    __syncthreads();
    for (int off = 1; off < 512; off <<= 1) {
        int x = (t >= off) ? lds[t - off] : 0;
        __syncthreads();
        lds[t] += x;
        __syncthreads();
    }
    int excl = lds[t] - v;
    if (t < NB) { boffs[t] = excl; gcur[t] = excl; }
    if (t == NB - 1) boffs[NB] = lds[t];           // == NE
}

// ---------------------------------------------------------------------------
// fp32 -> bf16 (round-nearest-even).
__device__ __forceinline__ short f2bf(float x)
{
    unsigned u = __float_as_uint(x);
    u += 0x7FFFu + ((u >> 16) & 1u);
    return (short)(u >> 16);
}

// ---------------------------------------------------------------------------
// FUSED dispatch: blocks [0,NTILES) run binscatter (bin edges into key/dl,
// grouped by coarse bucket); blocks [NTILES, NTILES+G1_BLOCKS) run gemm1
// (Y = feats@W1 -> fp8, MFMA, proven r18). Independent data -> true overlap.
__global__ __launch_bounds__(256) void k_bins_g1(const int* __restrict__ dst,
                                                 const int* __restrict__ esrc,
                                                 const float* __restrict__ ew,
                                                 int* __restrict__ gcur,
                                                 int* __restrict__ key,
                                                 unsigned char* __restrict__ dl,
                                                 const float* __restrict__ feats,
                                                 const float* __restrict__ W1,
                                                 unsigned char* __restrict__ Yq)
{
    __shared__ int           hist[NB];
    __shared__ int           cstart[NB];
    __shared__ int           ccur[NB];
    __shared__ int           gb[NB];
    __shared__ int           lds2[256];
    __shared__ int           sdst[TILE];
    __shared__ short         sbuck[TILE];
    __shared__ int           stage[TILE];
    __shared__ unsigned char sdl[TILE];

    int t = threadIdx.x;

    if (blockIdx.x < NTILES) {
        // ---- binscatter (proven r10 algorithm; packed key+dl payload) ----
        int base = blockIdx.x * TILE;
        int nvalid = NE - base; if (nvalid > TILE) nvalid = TILE;

        for (int i = t; i < NB; i += 256) hist[i] = 0;
        __syncthreads();
        for (int i = t; i < TILE; i += 256) {
            int e = base + i;
            int d = (e < NE) ? NTL(dst[e]) : -1;
            sdst[i] = d;
            if (d >= 0) atomicAdd(&hist[d >> 8], 1);
        }
        __syncthreads();

        int h0 = (2 * t     < NB) ? hist[2 * t]     : 0;
        int h1 = (2 * t + 1 < NB) ? hist[2 * t + 1] : 0;
        int ps = h0 + h1;
        lds2[t] = ps;
        __syncthreads();
        for (int off = 1; off < 256; off <<= 1) {
            int x = (t >= off) ? lds2[t - off] : 0;
            __syncthreads();
            lds2[t] += x;
            __syncthreads();
        }
        int excl = lds2[t] - ps;
        if (2 * t     < NB) { cstart[2 * t]     = excl;      ccur[2 * t]     = excl; }
        if (2 * t + 1 < NB) { cstart[2 * t + 1] = excl + h0; ccur[2 * t + 1] = excl + h0; }
        __syncthreads();

        for (int i = t; i < TILE; i += 256) {
            int d = sdst[i];
            if (d >= 0) {
                int e = base + i;
                int b = d >> 8;
                int pos = atomicAdd(&ccur[b], 1);
                unsigned wq = (unsigned)(NTL(ew[e]) * 32767.0f + 0.5f);
                stage[pos] = (int)(((unsigned)NTL(esrc[e]) << 15) | wq);
                sdl[pos] = (unsigned char)(d & 255);
                sbuck[pos] = (short)b;
            }
        }
        __syncthreads();

        for (int i = t; i < NB; i += 256)
            if (hist[i]) gb[i] = atomicAdd(&gcur[i], hist[i]);
        __syncthreads();
        for (int i = t; i < nvalid; i += 256) {
            int b = sbuck[i];
            int idx = gb[b] + (i - cstart[b]);
            key[idx] = stage[i];
            dl[idx] = sdl[i];
        }
    } else {
        // ---- gemm1 (MFMA, proven r18) ----
        int lane = t & 63;
        int wid = ((blockIdx.x - NTILES) * 256 + t) >> 6;  // 0..G1_WAVES-1
        int rc = lane & 15;
        int kg = lane >> 4;

        bf16x8 bfr[4][2];
        #pragma unroll
        for (int nt = 0; nt < 4; ++nt)
            #pragma unroll
            for (int kc = 0; kc < 2; ++kc) {
                int k0 = kc * 32 + kg * 8;
                #pragma unroll
                for (int b = 0; b < 8; ++b)
                    bfr[nt][kc][b] = f2bf(W1[(k0 + b) * 64 + nt * 16 + rc]);
            }

        for (int tt = wid; tt < G1_TILES; tt += G1_WAVES) {
            const float* ar = feats + (tt * 16 + rc) * 64;
            bf16x8 af[2];
            #pragma unroll
            for (int kc = 0; kc < 2; ++kc) {
                const float4 v0 = *(const float4*)(ar + kc * 32 + kg * 8);
                const float4 v1 = *(const float4*)(ar + kc * 32 + kg * 8 + 4);
                af[kc][0] = f2bf(v0.x); af[kc][1] = f2bf(v0.y);
                af[kc][2] = f2bf(v0.z); af[kc][3] = f2bf(v0.w);
                af[kc][4] = f2bf(v1.x); af[kc][5] = f2bf(v1.y);
                af[kc][6] = f2bf(v1.z); af[kc][7] = f2bf(v1.w);
            }
            #pragma unroll
            for (int nt = 0; nt < 4; ++nt) {
                f32x4 acc = {0.f, 0.f, 0.f, 0.f};
                acc = __builtin_amdgcn_mfma_f32_16x16x32_bf16(af[0], bfr[nt][0], acc, 0, 0, 0);
                acc = __builtin_amdgcn_mfma_f32_16x16x32_bf16(af[1], bfr[nt][1], acc, 0, 0, 0);
                #pragma unroll
                for (int r = 0; r < 4; ++r) {
                    int orow = tt * 16 + kg * 4 + r;
                    int b8 = __builtin_amdgcn_cvt_pk_fp8_f32(acc[r], acc[r], 0, false) & 0xFF;
                    Yq[orow * 64 + nt * 16 + rc] = (unsigned char)b8;
                }
            }
        }
    }
}

// ---------------------------------------------------------------------------
// B: per-bucket LDS counting sort (simplified r21: pass1 reads only dl;
// pass2 permutes csr-ready key, no repacking).
__global__ __launch_bounds__(256) void k_bucketsort(const int* __restrict__ key,
                                                    const unsigned char* __restrict__ dl,
                                                    const int* __restrict__ boffs,
                                                    int* __restrict__ offs,
                                                    int* __restrict__ csrp)
{
    __shared__ int nhist[256];
    __shared__ int ncur[256];
    __shared__ int lds[256];
    __shared__ int stage[CAP];

    int t = threadIdx.x, b = blockIdx.x;           // grid = NB
    int s0 = boffs[b], s1 = boffs[b + 1];
    int cnt = s1 - s0;

    nhist[t] = 0;
    __syncthreads();
    for (int i = t; i < cnt; i += 256)
        atomicAdd(&nhist[dl[s0 + i]], 1);
    __syncthreads();

    int v = nhist[t];
    lds[t] = v;
    __syncthreads();
    for (int off = 1; off < 256; off <<= 1) {
        int x = (t >= off) ? lds[t - off] : 0;
        __syncthreads();
        lds[t] += x;
        __syncthreads();
    }
    int excl = lds[t] - v;
    ncur[t] = excl;
    int node = b * 256 + t;
    if (node < NN) offs[node] = s0 + excl;
    if (b == NB - 1 && t == 0) offs[NN] = s1;      // == NE
    __syncthreads();

    for (int i = t; i < cnt; i += 256) {
        int d = dl[s0 + i];
        int pos = atomicAdd(&ncur[d], 1);
        stage[pos] = key[s0 + i];
    }
    __syncthreads();
    for (int i = t; i < cnt; i += 256)
        csrp[s0 + i] = stage[i];                   // fully coalesced
}

#define WDEC(c) ((float)((c) & 0x7fffu) * (1.0f / 32767.0f))

// ---------------------------------------------------------------------------
// Layer 1 (proven round 20): FOUR nodes per wave; 4 edge-slots x 16 lanes x
// 4B fp8; 8-shfl reduce; W2 MLP via LDS stage.
__global__ __launch_bounds__(256) void k_l1(const int* __restrict__ offs,
                                            const int* __restrict__ csrp,
                                            const unsigned char* __restrict__ Yq,
                                            const float* __restrict__ b1,
                                            const float* __restrict__ W2,
                                            __half* __restrict__ hw)
{
    __shared__ __align__(16) float sh[4][4][64];   // per-wave, per-node h stage
    int tid = threadIdx.x;
    int lane = tid & 63;
    int wv = tid >> 6;
    int wid = blockIdx.x * 4 + wv;                 // grid exact = NN/4 waves
    int n0 = wid * 4;
    int half = lane >> 5, c = lane & 31;

    float w2r[32];
    #pragma unroll
    for (int kk = 0; kk < 32; ++kk)
        w2r[kk] = W2[(half * 32 + kk) * 32 + c];

    int sub = lane >> 4;          // edge slot 0..3
    int e4  = lane & 15;          // col quad: cols [4*e4, 4*e4+4)
    const float4 bq = *(const float4*)(b1 + (e4 << 2));

    int sA = offs[n0],     eA = offs[n0 + 1];
    int sB = offs[n0 + 1], eB = offs[n0 + 2];
    int sC = offs[n0 + 2], eC = offs[n0 + 3];
    int sD = offs[n0 + 3], eD = offs[n0 + 4];

    float a0=0.f,a1=0.f,a2=0.f,a3=0.f;             // node A
    float g0=0.f,g1=0.f,g2=0.f,g3=0.f;             // node B
    float q0=0.f,q1=0.f,q2=0.f,q3=0.f;             // node C
    float r0=0.f,r1=0.f,r2=0.f,r3=0.f;             // node D
    for (int bA=sA, bB=sB, bC=sC, bD=sD;
         bA < eA || bB < eB || bC < eC || bD < eD;
         bA += 64, bB += 64, bC += 64, bD += 64) {
        int mA = eA-bA; mA = mA<0?0:(mA>64?64:mA);
        int mB = eB-bB; mB = mB<0?0:(mB>64?64:mB);
        int mC = eC-bC; mC = mC<0?0:(mC>64?64:mC);
        int mD = eD-bD; mD = mD<0?0:(mD>64?64:mD);
        int edA = (lane < mA) ? NTL(csrp[bA + lane]) : 0;   // pad: s=0, w=0
        int edB = (lane < mB) ? NTL(csrp[bB + lane]) : 0;
        int edC = (lane < mC) ? NTL(csrp[bC + lane]) : 0;
        int edD = (lane < mD) ? NTL(csrp[bD + lane]) : 0;
        int it = (mA+3)>>2;
        int t2 = (mB+3)>>2; if (t2 > it) it = t2;
        t2 = (mC+3)>>2; if (t2 > it) it = t2;
        t2 = (mD+3)>>2; if (t2 > it) it = t2;
        for (int i = 0; i < it; ++i) {
            int j = (i << 2) + sub;
            unsigned cA = (unsigned)__shfl(edA, j, 64);
            unsigned cB = (unsigned)__shfl(edB, j, 64);
            unsigned cC = (unsigned)__shfl(edC, j, 64);
            unsigned cD = (unsigned)__shfl(edD, j, 64);
            unsigned wA8 = *(const unsigned*)(Yq + (cA >> 15) * 64 + (e4 << 2));
            unsigned wB8 = *(const unsigned*)(Yq + (cB >> 15) * 64 + (e4 << 2));
            unsigned wC8 = *(const unsigned*)(Yq + (cC >> 15) * 64 + (e4 << 2));
            unsigned wD8 = *(const unsigned*)(Yq + (cD >> 15) * 64 + (e4 << 2));
            float wA = WDEC(cA), wB = WDEC(cB), wC = WDEC(cC), wD = WDEC(cD);
            fvec2 lo, hi;
            lo = __builtin_amdgcn_cvt_pk_f32_fp8((int)wA8, false);
            hi = __builtin_amdgcn_cvt_pk_f32_fp8((int)wA8, true);
            a0 = fmaf(wA, lo.x, a0); a1 = fmaf(wA, lo.y, a1);
            a2 = fmaf(wA, hi.x, a2); a3 = fmaf(wA, hi.y, a3);
            lo = __builtin_amdgcn_cvt_pk_f32_fp8((int)wB8, false);
            hi = __builtin_amdgcn_cvt_pk_f32_fp8((int)wB8, true);
            g0 = fmaf(wB, lo.x, g0); g1 = fmaf(wB, lo.y, g1);
            g2 = fmaf(wB, hi.x, g2); g3 = fmaf(wB, hi.y, g3);
            lo = __builtin_amdgcn_cvt_pk_f32_fp8((int)wC8, false);
            hi = __builtin_amdgcn_cvt_pk_f32_fp8((int)wC8, true);
            q0 = fmaf(wC, lo.x, q0); q1 = fmaf(wC, lo.y, q1);
            q2 = fmaf(wC, hi.x, q2); q3 = fmaf(wC, hi.y, q3);
            lo = __builtin_amdgcn_cvt_pk_f32_fp8((int)wD8, false);
            hi = __builtin_amdgcn_cvt_pk_f32_fp8((int)wD8, true);
            r0 = fmaf(wD, lo.x, r0); r1 = fmaf(wD, lo.y, r1);
            r2 = fmaf(wD, hi.x, r2); r3 = fmaf(wD, hi.y, r3);
        }
    }
    #define REDL1(x) x += __shfl_xor(x, 16, 64); x += __shfl_xor(x, 32, 64);
    REDL1(a0) REDL1(a1) REDL1(a2) REDL1(a3)
    REDL1(g0) REDL1(g1) REDL1(g2) REDL1(g3)
    REDL1(q0) REDL1(q1) REDL1(q2) REDL1(q3)
    REDL1(r0) REDL1(r1) REDL1(r2) REDL1(r3)

    #define LRELU(x) ((x) >= 0.f ? (x) : NEG_SLOPE * (x))
    if (sub == 0) {
        *(float4*)&sh[wv][0][e4 << 2] = make_float4(
            LRELU(a0 + bq.x), LRELU(a1 + bq.y), LRELU(a2 + bq.z), LRELU(a3 + bq.w));
        *(float4*)&sh[wv][1][e4 << 2] = make_float4(
            LRELU(g0 + bq.x), LRELU(g1 + bq.y), LRELU(g2 + bq.z), LRELU(g3 + bq.w));
        *(float4*)&sh[wv][2][e4 << 2] = make_float4(
            LRELU(q0 + bq.x), LRELU(q1 + bq.y), LRELU(q2 + bq.z), LRELU(q3 + bq.w));
        *(float4*)&sh[wv][3][e4 << 2] = make_float4(
            LRELU(r0 + bq.x), LRELU(r1 + bq.y), LRELU(r2 + bq.z), LRELU(r3 + bq.w));
    }
    __builtin_amdgcn_wave_barrier();               // keep writes before reads

    float pA = 0.f, pB = 0.f, pC = 0.f, pD = 0.f;
    #pragma unroll
    for (int q = 0; q < 8; ++q) {                  // broadcast reads
        float4 hvA = *(const float4*)&sh[wv][0][(half << 5) + (q << 2)];
        float4 hvB = *(const float4*)&sh[wv][1][(half << 5) + (q << 2)];
        float4 hvC = *(const float4*)&sh[wv][2][(half << 5) + (q << 2)];
        float4 hvD = *(const float4*)&sh[wv][3][(half << 5) + (q << 2)];
        pA = fmaf(hvA.x, w2r[4*q+0], pA); pB = fmaf(hvB.x, w2r[4*q+0], pB);
        pC = fmaf(hvC.x, w2r[4*q+0], pC); pD = fmaf(hvD.x, w2r[4*q+0], pD);
        pA = fmaf(hvA.y, w2r[4*q+1], pA); pB = fmaf(hvB.y, w2r[4*q+1], pB);
        pC = fmaf(hvC.y, w2r[4*q+1], pC); pD = fmaf(hvD.y, w2r[4*q+1], pD);
        pA = fmaf(hvA.z, w2r[4*q+2], pA); pB = fmaf(hvB.z, w2r[4*q+2], pB);
        pC = fmaf(hvC.z, w2r[4*q+2], pC); pD = fmaf(hvD.z, w2r[4*q+2], pD);
        pA = fmaf(hvA.w, w2r[4*q+3], pA); pB = fmaf(hvB.w, w2r[4*q+3], pB);
        pC = fmaf(hvC.w, w2r[4*q+3], pC); pD = fmaf(hvD.w, w2r[4*q+3], pD);
    }
    pA += __shfl_xor(pA, 32, 64);
    pB += __shfl_xor(pB, 32, 64);
    pC += __shfl_xor(pC, 32, 64);
    pD += __shfl_xor(pD, 32, 64);
    if (lane < 32) {
        hw[(n0 + 0) * 32 + lane] = __float2half(pA);
        hw[(n0 + 1) * 32 + lane] = __float2half(pB);
        hw[(n0 + 2) * 32 + lane] = __float2half(pC);
        hw[(n0 + 3) * 32 + lane] = __float2half(pD);
    }
}

// ---------------------------------------------------------------------------
// Layer 2 (proven round 20): FOUR nodes per wave; 8 edge-slots x 8 lanes x
// 8B fp16, 4 accumulators, 12-shfl RED; NT store.
__global__ __launch_bounds__(256) void k_l2(const int* __restrict__ offs,
                                            const int* __restrict__ csrp,
                                            const __half* __restrict__ hw,
                                            const float* __restrict__ b2,
                                            float* __restrict__ out)
{
    int tid = threadIdx.x;
    int lane = tid & 63;
    int wid = blockIdx.x * 4 + (tid >> 6);         // grid exact = NN/4 waves
    int n0 = wid * 4;
    int sub = lane >> 3;          // edge slot 0..7
    int e4  = lane & 7;           // col quad: cols [4*e4, 4*e4+4)
    const float4 bq = *(const float4*)(b2 + (e4 << 2));

    int sA = offs[n0],     eA = offs[n0 + 1];
    int sB = offs[n0 + 1], eB = offs[n0 + 2];
    int sC = offs[n0 + 2], eC = offs[n0 + 3];
    int sD = offs[n0 + 3], eD = offs[n0 + 4];

    float a0=0.f,a1=0.f,a2=0.f,a3=0.f;
    float g0=0.f,g1=0.f,g2=0.f,g3=0.f;
    float q0=0.f,q1=0.f,q2=0.f,q3=0.f;
    float r0=0.f,r1=0.f,r2=0.f,r3=0.f;
    for (int bA=sA, bB=sB, bC=sC, bD=sD;
         bA < eA || bB < eB || bC < eC || bD < eD;
         bA += 64, bB += 64, bC += 64, bD += 64) {
        int mA = eA-bA; mA = mA<0?0:(mA>64?64:mA);
        int mB = eB-bB; mB = mB<0?0:(mB>64?64:mB);
        int mC = eC-bC; mC = mC<0?0:(mC>64?64:mC);
        int mD = eD-bD; mD = mD<0?0:(mD>64?64:mD);
        int edA = (lane < mA) ? NTL(csrp[bA + lane]) : 0;   // pad: s=0, w=0
        int edB = (lane < mB) ? NTL(csrp[bB + lane]) : 0;
        int edC = (lane < mC) ? NTL(csrp[bC + lane]) : 0;
        int edD = (lane < mD) ? NTL(csrp[bD + lane]) : 0;
        int it = (mA+7)>>3;
        int t2 = (mB+7)>>3; if (t2 > it) it = t2;
        t2 = (mC+7)>>3; if (t2 > it) it = t2;
        t2 = (mD+7)>>3; if (t2 > it) it = t2;
        for (int i = 0; i < it; ++i) {
            int j = (i << 3) + sub;
            unsigned cA = (unsigned)__shfl(edA, j, 64);
            unsigned cB = (unsigned)__shfl(edB, j, 64);
            unsigned cC = (unsigned)__shfl(edC, j, 64);
            unsigned cD = (unsigned)__shfl(edD, j, 64);
            int2 rA = *(const int2*)(hw + (cA >> 15) * 32 + (e4 << 2));
            int2 rB = *(const int2*)(hw + (cB >> 15) * 32 + (e4 << 2));
            int2 rC = *(const int2*)(hw + (cC >> 15) * 32 + (e4 << 2));
            int2 rD = *(const int2*)(hw + (cD >> 15) * 32 + (e4 << 2));
            float wA = WDEC(cA), wB = WDEC(cB), wC = WDEC(cC), wD = WDEC(cD);
            float2 f0, f1;
            f0 = __half22float2(((const __half2*)&rA)[0]);
            f1 = __half22float2(((const __half2*)&rA)[1]);
            a0 = fmaf(wA, f0.x, a0); a1 = fmaf(wA, f0.y, a1);
            a2 = fmaf(wA, f1.x, a2); a3 = fmaf(wA, f1.y, a3);
            f0 = __half22float2(((const __half2*)&rB)[0]);
            f1 = __half22float2(((const __half2*)&rB)[1]);
            g0 = fmaf(wB, f0.x, g0); g1 = fmaf(wB, f0.y, g1);
            g2 = fmaf(wB, f1.x, g2); g3 = fmaf(wB, f1.y, g3);
            f0 = __half22float2(((const __half2*)&rC)[0]);
            f1 = __half22float2(((const __half2*)&rC)[1]);
            q0 = fmaf(wC, f0.x, q0); q1 = fmaf(wC, f0.y, q1);
            q2 = fmaf(wC, f1.x, q2); q3 = fmaf(wC, f1.y, q3);
            f0 = __half22float2(((const __half2*)&rD)[0]);
            f1 = __half22float2(((const __half2*)&rD)[1]);
            r0 = fmaf(wD, f0.x, r0); r1 = fmaf(wD, f0.y, r1);
            r2 = fmaf(wD, f1.x, r2); r3 = fmaf(wD, f1.y, r3);
        }
    }
    #define REDL2(x) x += __shfl_xor(x, 8, 64); x += __shfl_xor(x, 16, 64); \
                     x += __shfl_xor(x, 32, 64);
    REDL2(a0) REDL2(a1) REDL2(a2) REDL2(a3)
    REDL2(g0) REDL2(g1) REDL2(g2) REDL2(g3)
    REDL2(q0) REDL2(q1) REDL2(q2) REDL2(q3)
    REDL2(r0) REDL2(r1) REDL2(r2) REDL2(r3)

    if (sub == 0) {
        fvec4 oA = { a0 + bq.x, a1 + bq.y, a2 + bq.z, a3 + bq.w };
        fvec4 oB = { g0 + bq.x, g1 + bq.y, g2 + bq.z, g3 + bq.w };
        fvec4 oC = { q0 + bq.x, q1 + bq.y, q2 + bq.z, q3 + bq.w };
        fvec4 oD = { r0 + bq.x, r1 + bq.y, r2 + bq.z, r3 + bq.w };
        __builtin_nontemporal_store(oA, (fvec4*)(out + (n0+0) * 32 + (e4 << 2)));
        __builtin_nontemporal_store(oB, (fvec4*)(out + (n0+1) * 32 + (e4 << 2)));
        __builtin_nontemporal_store(oC, (fvec4*)(out + (n0+2) * 32 + (e4 << 2)));
        __builtin_nontemporal_store(oD, (fvec4*)(out + (n0+3) * 32 + (e4 << 2)));
    }
}

// ---------------------------------------------------------------------------
extern "C" void kernel_launch(void* const* d_in, const int* in_sizes, int n_in,
                              void* d_out, int out_size, void* d_ws, size_t ws_size,
                              hipStream_t stream)
{
    const float* feats = (const float*)d_in[0];
    const int*   esrc  = (const int*)d_in[1];
    const int*   edst  = (const int*)d_in[2];
    const float* ew    = (const float*)d_in[3];
    const float* W1    = (const float*)d_in[4];
    const float* b1    = (const float*)d_in[5];
    const float* W2    = (const float*)d_in[6];
    const float* b2    = (const float*)d_in[7];
    float* out = (float*)d_out;

    char*          ws    = (char*)d_ws;
    int*           offs  = (int*)ws;
    int*           csrp  = (int*)(ws + OFF_CSR);
    int*           key   = (int*)(ws + OFF_KEY);
    unsigned char* dl    = (unsigned char*)(ws + OFF_DL);
    unsigned char* Yq    = (unsigned char*)(ws + OFF_YQ);
    int*           bcnt  = (int*)(ws + OFF_BCNT);
    int*           boffs = (int*)(ws + OFF_BOFFS);
    int*           gcur  = (int*)(ws + OFF_GCUR);
    __half*        hw    = (__half*)(ws + OFF_HW);   // aliases key (dead post-sort)

    (void)hipMemsetAsync(bcnt, 0, NB * sizeof(int), stream);

    k_bucketcnt <<<NTILES,             256, 0, stream>>>(edst, bcnt);
    k_bucketscan<<<1,                  512, 0, stream>>>(bcnt, boffs, gcur);
    k_bins_g1   <<<NTILES + G1_BLOCKS, 256, 0, stream>>>(edst, esrc, ew, gcur,
                                                         key, dl, feats, W1, Yq);
    k_bucketsort<<<NB,                 256, 0, stream>>>(key, dl, boffs, offs, csrp);
    k_l1        <<<NN / 16,            256, 0, stream>>>(offs, csrp, Yq, b1, W2, hw);
    k_l2        <<<NN / 16,            256, 0, stream>>>(offs, csrp, hw, b2, out);
}

// Round 22
// 138.971 us; speedup vs baseline: 1.7208x; 1.0127x over previous
//
#include <hip/hip_runtime.h>
#include <hip/hip_fp16.h>

#define NN 100000
#define NE 1600000
#define NEG_SLOPE 0.01f

#define NTL(x) __builtin_nontemporal_load(&(x))
typedef float fvec4 __attribute__((ext_vector_type(4)));
typedef float fvec2 __attribute__((ext_vector_type(2)));
typedef short bf16x8 __attribute__((ext_vector_type(8)));
typedef float f32x4 __attribute__((ext_vector_type(4)));

// Coarse buckets: 256 consecutive dst nodes each.
#define NB     391        // ceil(NN/256)
#define TILE   4096       // edges per binning workgroup
#define NTILES 391        // ceil(NE/TILE)
#define CAP    8192       // LDS stage capacity per bucket

// gemm1 (MFMA, fused into binscatter dispatch): 512 blocks = 2048 waves.
#define G1_BLOCKS 512
#define G1_WAVES  (G1_BLOCKS * 4)
#define G1_TILES  6250    // NN / 16 exactly

// ---------------------------------------------------------------------------
// Workspace layout (bytes) — total ~21.3 MB (< 26.4 MB proven).
//   offs : (NN+1) int   @ 0            (400,004 -> pad 400,384)
//   csrp : NE int       @ 400,384      (6.4 MB)
//   key  : NE int       @ 6,808,384    (src<<15|wq; 6.4 MB; later hw)
//   dl   : NE uchar     @ 13,208,384   (1.6 MB)
//   Yq   : NN*64 fp8    @ 14,808,384   (6.4 MB, own region)
//   bcnt : NB int       @ 21,208,384
//   boffs: (NB+1) int   @ 21,210,432
//   gcur : NB int       @ 21,212,480
#define OFF_CSR   400384
#define OFF_KEY   6808384
#define OFF_DL    13208384
#define OFF_YQ    14808384
#define OFF_BCNT  21208384
#define OFF_BOFFS 21210432
#define OFF_GCUR  21212480
#define OFF_HW    OFF_KEY     // hw aliases key

// ---------------------------------------------------------------------------
// Round 22: custom zeroing kernel replaces hipMemsetAsync(bcnt) — the rocclr
// fillBuffer node showed dur ~42.7us in r20/r21 profiles (either real serial
// cost or a concurrency artifact; this isolates which).
__global__ __launch_bounds__(512) void k_zero(int* __restrict__ bcnt)
{
    int t = threadIdx.x;
    if (t < NB) bcnt[t] = 0;
}

// ---------------------------------------------------------------------------
// A1: per-bucket edge counts (proven round 10).
__global__ __launch_bounds__(256) void k_bucketcnt(const int* __restrict__ dst,
                                                   int* __restrict__ bcnt)
{
    __shared__ int h[NB];
    int t = threadIdx.x;
    for (int i = t; i < NB; i += 256) h[i] = 0;
    __syncthreads();
    int base = blockIdx.x * TILE;
    for (int i = t; i < TILE; i += 256) {
        int e = base + i;
        if (e < NE) atomicAdd(&h[NTL(dst[e]) >> 8], 1);
    }
    __syncthreads();
    for (int i = t; i < NB; i += 256)
        if (h[i]) atomicAdd(&bcnt[i], h[i]);
}

// A2: exclusive scan of bucket counts (proven round 10).
__global__ __launch_bounds__(512) void k_bucketscan(const int* __restrict__ bcnt,
                                                    int* __restrict__ boffs,
                                                    int* __restrict__ gcur)
{
    __shared__ int lds[512];
    int t = threadIdx.x;
    int v = (t < NB) ? bcnt[t] : 0;
    lds[t] = v;
    __syncthreads();
    for (int off = 1; off < 512; off <<= 1) {
        int x = (t >= off) ? lds[t - off] : 0;
        __syncthreads();
        lds[t] += x;
        __syncthreads();
    }
    int excl = lds[t] - v;
    if (t < NB) { boffs[t] = excl; gcur[t] = excl; }
    if (t == NB - 1) boffs[NB] = lds[t];           // == NE
}

// ---------------------------------------------------------------------------
// fp32 -> bf16 (round-nearest-even).
__device__ __forceinline__ short f2bf(float x)
{
    unsigned u = __float_as_uint(x);
    u += 0x7FFFu + ((u >> 16) & 1u);
    return (short)(u >> 16);
}

// ---------------------------------------------------------------------------
// FUSED dispatch: blocks [0,NTILES) run binscatter; blocks [NTILES,
// NTILES+G1_BLOCKS) run gemm1 (MFMA, proven r18). Independent data.
__global__ __launch_bounds__(256) void k_bins_g1(const int* __restrict__ dst,
                                                 const int* __restrict__ esrc,
                                                 const float* __restrict__ ew,
                                                 int* __restrict__ gcur,
                                                 int* __restrict__ key,
                                                 unsigned char* __restrict__ dl,
                                                 const float* __restrict__ feats,
                                                 const float* __restrict__ W1,
                                                 unsigned char* __restrict__ Yq)
{
    __shared__ int           hist[NB];
    __shared__ int           cstart[NB];
    __shared__ int           ccur[NB];
    __shared__ int           gb[NB];
    __shared__ int           lds2[256];
    __shared__ int           sdst[TILE];
    __shared__ short         sbuck[TILE];
    __shared__ int           stage[TILE];
    __shared__ unsigned char sdl[TILE];

    int t = threadIdx.x;

    if (blockIdx.x < NTILES) {
        int base = blockIdx.x * TILE;
        int nvalid = NE - base; if (nvalid > TILE) nvalid = TILE;

        for (int i = t; i < NB; i += 256) hist[i] = 0;
        __syncthreads();
        for (int i = t; i < TILE; i += 256) {
            int e = base + i;
            int d = (e < NE) ? NTL(dst[e]) : -1;
            sdst[i] = d;
            if (d >= 0) atomicAdd(&hist[d >> 8], 1);
        }
        __syncthreads();

        int h0 = (2 * t     < NB) ? hist[2 * t]     : 0;
        int h1 = (2 * t + 1 < NB) ? hist[2 * t + 1] : 0;
        int ps = h0 + h1;
        lds2[t] = ps;
        __syncthreads();
        for (int off = 1; off < 256; off <<= 1) {
            int x = (t >= off) ? lds2[t - off] : 0;
            __syncthreads();
            lds2[t] += x;
            __syncthreads();
        }
        int excl = lds2[t] - ps;
        if (2 * t     < NB) { cstart[2 * t]     = excl;      ccur[2 * t]     = excl; }
        if (2 * t + 1 < NB) { cstart[2 * t + 1] = excl + h0; ccur[2 * t + 1] = excl + h0; }
        __syncthreads();

        for (int i = t; i < TILE; i += 256) {
            int d = sdst[i];
            if (d >= 0) {
                int e = base + i;
                int b = d >> 8;
                int pos = atomicAdd(&ccur[b], 1);
                unsigned wq = (unsigned)(NTL(ew[e]) * 32767.0f + 0.5f);
                stage[pos] = (int)(((unsigned)NTL(esrc[e]) << 15) | wq);
                sdl[pos] = (unsigned char)(d & 255);
                sbuck[pos] = (short)b;
            }
        }
        __syncthreads();

        for (int i = t; i < NB; i += 256)
            if (hist[i]) gb[i] = atomicAdd(&gcur[i], hist[i]);
        __syncthreads();
        for (int i = t; i < nvalid; i += 256) {
            int b = sbuck[i];
            int idx = gb[b] + (i - cstart[b]);
            key[idx] = stage[i];
            dl[idx] = sdl[i];
        }
    } else {
        int lane = t & 63;
        int wid = ((blockIdx.x - NTILES) * 256 + t) >> 6;  // 0..G1_WAVES-1
        int rc = lane & 15;
        int kg = lane >> 4;

        bf16x8 bfr[4][2];
        #pragma unroll
        for (int nt = 0; nt < 4; ++nt)
            #pragma unroll
            for (int kc = 0; kc < 2; ++kc) {
                int k0 = kc * 32 + kg * 8;
                #pragma unroll
                for (int b = 0; b < 8; ++b)
                    bfr[nt][kc][b] = f2bf(W1[(k0 + b) * 64 + nt * 16 + rc]);
            }

        for (int tt = wid; tt < G1_TILES; tt += G1_WAVES) {
            const float* ar = feats + (tt * 16 + rc) * 64;
            bf16x8 af[2];
            #pragma unroll
            for (int kc = 0; kc < 2; ++kc) {
                const float4 v0 = *(const float4*)(ar + kc * 32 + kg * 8);
                const float4 v1 = *(const float4*)(ar + kc * 32 + kg * 8 + 4);
                af[kc][0] = f2bf(v0.x); af[kc][1] = f2bf(v0.y);
                af[kc][2] = f2bf(v0.z); af[kc][3] = f2bf(v0.w);
                af[kc][4] = f2bf(v1.x); af[kc][5] = f2bf(v1.y);
                af[kc][6] = f2bf(v1.z); af[kc][7] = f2bf(v1.w);
            }
            #pragma unroll
            for (int nt = 0; nt < 4; ++nt) {
                f32x4 acc = {0.f, 0.f, 0.f, 0.f};
                acc = __builtin_amdgcn_mfma_f32_16x16x32_bf16(af[0], bfr[nt][0], acc, 0, 0, 0);
                acc = __builtin_amdgcn_mfma_f32_16x16x32_bf16(af[1], bfr[nt][1], acc, 0, 0, 0);
                #pragma unroll
                for (int r = 0; r < 4; ++r) {
                    int orow = tt * 16 + kg * 4 + r;
                    int b8 = __builtin_amdgcn_cvt_pk_fp8_f32(acc[r], acc[r], 0, false) & 0xFF;
                    Yq[orow * 64 + nt * 16 + rc] = (unsigned char)b8;
                }
            }
        }
    }
}

// ---------------------------------------------------------------------------
// B: per-bucket LDS counting sort (proven r21 simplified form).
__global__ __launch_bounds__(256) void k_bucketsort(const int* __restrict__ key,
                                                    const unsigned char* __restrict__ dl,
                                                    const int* __restrict__ boffs,
                                                    int* __restrict__ offs,
                                                    int* __restrict__ csrp)
{
    __shared__ int nhist[256];
    __shared__ int ncur[256];
    __shared__ int lds[256];
    __shared__ int stage[CAP];

    int t = threadIdx.x, b = blockIdx.x;           // grid = NB
    int s0 = boffs[b], s1 = boffs[b + 1];
    int cnt = s1 - s0;

    nhist[t] = 0;
    __syncthreads();
    for (int i = t; i < cnt; i += 256)
        atomicAdd(&nhist[dl[s0 + i]], 1);
    __syncthreads();

    int v = nhist[t];
    lds[t] = v;
    __syncthreads();
    for (int off = 1; off < 256; off <<= 1) {
        int x = (t >= off) ? lds[t - off] : 0;
        __syncthreads();
        lds[t] += x;
        __syncthreads();
    }
    int excl = lds[t] - v;
    ncur[t] = excl;
    int node = b * 256 + t;
    if (node < NN) offs[node] = s0 + excl;
    if (b == NB - 1 && t == 0) offs[NN] = s1;      // == NE
    __syncthreads();

    for (int i = t; i < cnt; i += 256) {
        int d = dl[s0 + i];
        int pos = atomicAdd(&ncur[d], 1);
        stage[pos] = key[s0 + i];
    }
    __syncthreads();
    for (int i = t; i < cnt; i += 256)
        csrp[s0 + i] = stage[i];                   // fully coalesced
}

#define WDEC(c) ((float)((c) & 0x7fffu) * (1.0f / 32767.0f))

// ---------------------------------------------------------------------------
// Layer 1 (proven round 20): FOUR nodes per wave; 4 edge-slots x 16 lanes x
// 4B fp8; 8-shfl reduce; W2 MLP via LDS stage.
__global__ __launch_bounds__(256) void k_l1(const int* __restrict__ offs,
                                            const int* __restrict__ csrp,
                                            const unsigned char* __restrict__ Yq,
                                            const float* __restrict__ b1,
                                            const float* __restrict__ W2,
                                            __half* __restrict__ hw)
{
    __shared__ __align__(16) float sh[4][4][64];   // per-wave, per-node h stage
    int tid = threadIdx.x;
    int lane = tid & 63;
    int wv = tid >> 6;
    int wid = blockIdx.x * 4 + wv;                 // grid exact = NN/4 waves
    int n0 = wid * 4;
    int half = lane >> 5, c = lane & 31;

    float w2r[32];
    #pragma unroll
    for (int kk = 0; kk < 32; ++kk)
        w2r[kk] = W2[(half * 32 + kk) * 32 + c];

    int sub = lane >> 4;          // edge slot 0..3
    int e4  = lane & 15;          // col quad: cols [4*e4, 4*e4+4)
    const float4 bq = *(const float4*)(b1 + (e4 << 2));

    int sA = offs[n0],     eA = offs[n0 + 1];
    int sB = offs[n0 + 1], eB = offs[n0 + 2];
    int sC = offs[n0 + 2], eC = offs[n0 + 3];
    int sD = offs[n0 + 3], eD = offs[n0 + 4];

    float a0=0.f,a1=0.f,a2=0.f,a3=0.f;             // node A
    float g0=0.f,g1=0.f,g2=0.f,g3=0.f;             // node B
    float q0=0.f,q1=0.f,q2=0.f,q3=0.f;             // node C
    float r0=0.f,r1=0.f,r2=0.f,r3=0.f;             // node D
    for (int bA=sA, bB=sB, bC=sC, bD=sD;
         bA < eA || bB < eB || bC < eC || bD < eD;
         bA += 64, bB += 64, bC += 64, bD += 64) {
        int mA = eA-bA; mA = mA<0?0:(mA>64?64:mA);
        int mB = eB-bB; mB = mB<0?0:(mB>64?64:mB);
        int mC = eC-bC; mC = mC<0?0:(mC>64?64:mC);
        int mD = eD-bD; mD = mD<0?0:(mD>64?64:mD);
        int edA = (lane < mA) ? NTL(csrp[bA + lane]) : 0;   // pad: s=0, w=0
        int edB = (lane < mB) ? NTL(csrp[bB + lane]) : 0;
        int edC = (lane < mC) ? NTL(csrp[bC + lane]) : 0;
        int edD = (lane < mD) ? NTL(csrp[bD + lane]) : 0;
        int it = (mA+3)>>2;
        int t2 = (mB+3)>>2; if (t2 > it) it = t2;
        t2 = (mC+3)>>2; if (t2 > it) it = t2;
        t2 = (mD+3)>>2; if (t2 > it) it = t2;
        for (int i = 0; i < it; ++i) {
            int j = (i << 2) + sub;
            unsigned cA = (unsigned)__shfl(edA, j, 64);
            unsigned cB = (unsigned)__shfl(edB, j, 64);
            unsigned cC = (unsigned)__shfl(edC, j, 64);
            unsigned cD = (unsigned)__shfl(edD, j, 64);
            unsigned wA8 = *(const unsigned*)(Yq + (cA >> 15) * 64 + (e4 << 2));
            unsigned wB8 = *(const unsigned*)(Yq + (cB >> 15) * 64 + (e4 << 2));
            unsigned wC8 = *(const unsigned*)(Yq + (cC >> 15) * 64 + (e4 << 2));
            unsigned wD8 = *(const unsigned*)(Yq + (cD >> 15) * 64 + (e4 << 2));
            float wA = WDEC(cA), wB = WDEC(cB), wC = WDEC(cC), wD = WDEC(cD);
            fvec2 lo, hi;
            lo = __builtin_amdgcn_cvt_pk_f32_fp8((int)wA8, false);
            hi = __builtin_amdgcn_cvt_pk_f32_fp8((int)wA8, true);
            a0 = fmaf(wA, lo.x, a0); a1 = fmaf(wA, lo.y, a1);
            a2 = fmaf(wA, hi.x, a2); a3 = fmaf(wA, hi.y, a3);
            lo = __builtin_amdgcn_cvt_pk_f32_fp8((int)wB8, false);
            hi = __builtin_amdgcn_cvt_pk_f32_fp8((int)wB8, true);
            g0 = fmaf(wB, lo.x, g0); g1 = fmaf(wB, lo.y, g1);
            g2 = fmaf(wB, hi.x, g2); g3 = fmaf(wB, hi.y, g3);
            lo = __builtin_amdgcn_cvt_pk_f32_fp8((int)wC8, false);
            hi = __builtin_amdgcn_cvt_pk_f32_fp8((int)wC8, true);
            q0 = fmaf(wC, lo.x, q0); q1 = fmaf(wC, lo.y, q1);
            q2 = fmaf(wC, hi.x, q2); q3 = fmaf(wC, hi.y, q3);
            lo = __builtin_amdgcn_cvt_pk_f32_fp8((int)wD8, false);
            hi = __builtin_amdgcn_cvt_pk_f32_fp8((int)wD8, true);
            r0 = fmaf(wD, lo.x, r0); r1 = fmaf(wD, lo.y, r1);
            r2 = fmaf(wD, hi.x, r2); r3 = fmaf(wD, hi.y, r3);
        }
    }
    #define REDL1(x) x += __shfl_xor(x, 16, 64); x += __shfl_xor(x, 32, 64);
    REDL1(a0) REDL1(a1) REDL1(a2) REDL1(a3)
    REDL1(g0) REDL1(g1) REDL1(g2) REDL1(g3)
    REDL1(q0) REDL1(q1) REDL1(q2) REDL1(q3)
    REDL1(r0) REDL1(r1) REDL1(r2) REDL1(r3)

    #define LRELU(x) ((x) >= 0.f ? (x) : NEG_SLOPE * (x))
    if (sub == 0) {
        *(float4*)&sh[wv][0][e4 << 2] = make_float4(
            LRELU(a0 + bq.x), LRELU(a1 + bq.y), LRELU(a2 + bq.z), LRELU(a3 + bq.w));
        *(float4*)&sh[wv][1][e4 << 2] = make_float4(
            LRELU(g0 + bq.x), LRELU(g1 + bq.y), LRELU(g2 + bq.z), LRELU(g3 + bq.w));
        *(float4*)&sh[wv][2][e4 << 2] = make_float4(
            LRELU(q0 + bq.x), LRELU(q1 + bq.y), LRELU(q2 + bq.z), LRELU(q3 + bq.w));
        *(float4*)&sh[wv][3][e4 << 2] = make_float4(
            LRELU(r0 + bq.x), LRELU(r1 + bq.y), LRELU(r2 + bq.z), LRELU(r3 + bq.w));
    }
    __builtin_amdgcn_wave_barrier();               // keep writes before reads

    float pA = 0.f, pB = 0.f, pC = 0.f, pD = 0.f;
    #pragma unroll
    for (int q = 0; q < 8; ++q) {                  // broadcast reads
        float4 hvA = *(const float4*)&sh[wv][0][(half << 5) + (q << 2)];
        float4 hvB = *(const float4*)&sh[wv][1][(half << 5) + (q << 2)];
        float4 hvC = *(const float4*)&sh[wv][2][(half << 5) + (q << 2)];
        float4 hvD = *(const float4*)&sh[wv][3][(half << 5) + (q << 2)];
        pA = fmaf(hvA.x, w2r[4*q+0], pA); pB = fmaf(hvB.x, w2r[4*q+0], pB);
        pC = fmaf(hvC.x, w2r[4*q+0], pC); pD = fmaf(hvD.x, w2r[4*q+0], pD);
        pA = fmaf(hvA.y, w2r[4*q+1], pA); pB = fmaf(hvB.y, w2r[4*q+1], pB);
        pC = fmaf(hvC.y, w2r[4*q+1], pC); pD = fmaf(hvD.y, w2r[4*q+1], pD);
        pA = fmaf(hvA.z, w2r[4*q+2], pA); pB = fmaf(hvB.z, w2r[4*q+2], pB);
        pC = fmaf(hvC.z, w2r[4*q+2], pC); pD = fmaf(hvD.z, w2r[4*q+2], pD);
        pA = fmaf(hvA.w, w2r[4*q+3], pA); pB = fmaf(hvB.w, w2r[4*q+3], pB);
        pC = fmaf(hvC.w, w2r[4*q+3], pC); pD = fmaf(hvD.w, w2r[4*q+3], pD);
    }
    pA += __shfl_xor(pA, 32, 64);
    pB += __shfl_xor(pB, 32, 64);
    pC += __shfl_xor(pC, 32, 64);
    pD += __shfl_xor(pD, 32, 64);
    if (lane < 32) {
        hw[(n0 + 0) * 32 + lane] = __float2half(pA);
        hw[(n0 + 1) * 32 + lane] = __float2half(pB);
        hw[(n0 + 2) * 32 + lane] = __float2half(pC);
        hw[(n0 + 3) * 32 + lane] = __float2half(pD);
    }
}

// ---------------------------------------------------------------------------
// Layer 2 (proven round 20): FOUR nodes per wave; 8 edge-slots x 8 lanes x
// 8B fp16, 4 accumulators, 12-shfl RED; NT store.
__global__ __launch_bounds__(256) void k_l2(const int* __restrict__ offs,
                                            const int* __restrict__ csrp,
                                            const __half* __restrict__ hw,
                                            const float* __restrict__ b2,
                                            float* __restrict__ out)
{
    int tid = threadIdx.x;
    int lane = tid & 63;
    int wid = blockIdx.x * 4 + (tid >> 6);         // grid exact = NN/4 waves
    int n0 = wid * 4;
    int sub = lane >> 3;          // edge slot 0..7
    int e4  = lane & 7;           // col quad: cols [4*e4, 4*e4+4)
    const float4 bq = *(const float4*)(b2 + (e4 << 2));

    int sA = offs[n0],     eA = offs[n0 + 1];
    int sB = offs[n0 + 1], eB = offs[n0 + 2];
    int sC = offs[n0 + 2], eC = offs[n0 + 3];
    int sD = offs[n0 + 3], eD = offs[n0 + 4];

    float a0=0.f,a1=0.f,a2=0.f,a3=0.f;
    float g0=0.f,g1=0.f,g2=0.f,g3=0.f;
    float q0=0.f,q1=0.f,q2=0.f,q3=0.f;
    float r0=0.f,r1=0.f,r2=0.f,r3=0.f;
    for (int bA=sA, bB=sB, bC=sC, bD=sD;
         bA < eA || bB < eB || bC < eC || bD < eD;
         bA += 64, bB += 64, bC += 64, bD += 64) {
        int mA = eA-bA; mA = mA<0?0:(mA>64?64:mA);
        int mB = eB-bB; mB = mB<0?0:(mB>64?64:mB);
        int mC = eC-bC; mC = mC<0?0:(mC>64?64:mC);
        int mD = eD-bD; mD = mD<0?0:(mD>64?64:mD);
        int edA = (lane < mA) ? NTL(csrp[bA + lane]) : 0;   // pad: s=0, w=0
        int edB = (lane < mB) ? NTL(csrp[bB + lane]) : 0;
        int edC = (lane < mC) ? NTL(csrp[bC + lane]) : 0;
        int edD = (lane < mD) ? NTL(csrp[bD + lane]) : 0;
        int it = (mA+7)>>3;
        int t2 = (mB+7)>>3; if (t2 > it) it = t2;
        t2 = (mC+7)>>3; if (t2 > it) it = t2;
        t2 = (mD+7)>>3; if (t2 > it) it = t2;
        for (int i = 0; i < it; ++i) {
            int j = (i << 3) + sub;
            unsigned cA = (unsigned)__shfl(edA, j, 64);
            unsigned cB = (unsigned)__shfl(edB, j, 64);
            unsigned cC = (unsigned)__shfl(edC, j, 64);
            unsigned cD = (unsigned)__shfl(edD, j, 64);
            int2 rA = *(const int2*)(hw + (cA >> 15) * 32 + (e4 << 2));
            int2 rB = *(const int2*)(hw + (cB >> 15) * 32 + (e4 << 2));
            int2 rC = *(const int2*)(hw + (cC >> 15) * 32 + (e4 << 2));
            int2 rD = *(const int2*)(hw + (cD >> 15) * 32 + (e4 << 2));
            float wA = WDEC(cA), wB = WDEC(cB), wC = WDEC(cC), wD = WDEC(cD);
            float2 f0, f1;
            f0 = __half22float2(((const __half2*)&rA)[0]);
            f1 = __half22float2(((const __half2*)&rA)[1]);
            a0 = fmaf(wA, f0.x, a0); a1 = fmaf(wA, f0.y, a1);
            a2 = fmaf(wA, f1.x, a2); a3 = fmaf(wA, f1.y, a3);
            f0 = __half22float2(((const __half2*)&rB)[0]);
            f1 = __half22float2(((const __half2*)&rB)[1]);
            g0 = fmaf(wB, f0.x, g0); g1 = fmaf(wB, f0.y, g1);
            g2 = fmaf(wB, f1.x, g2); g3 = fmaf(wB, f1.y, g3);
            f0 = __half22float2(((const __half2*)&rC)[0]);
            f1 = __half22float2(((const __half2*)&rC)[1]);
            q0 = fmaf(wC, f0.x, q0); q1 = fmaf(wC, f0.y, q1);
            q2 = fmaf(wC, f1.x, q2); q3 = fmaf(wC, f1.y, q3);
            f0 = __half22float2(((const __half2*)&rD)[0]);
            f1 = __half22float2(((const __half2*)&rD)[1]);
            r0 = fmaf(wD, f0.x, r0); r1 = fmaf(wD, f0.y, r1);
            r2 = fmaf(wD, f1.x, r2); r3 = fmaf(wD, f1.y, r3);
        }
    }
    #define REDL2(x) x += __shfl_xor(x, 8, 64); x += __shfl_xor(x, 16, 64); \
                     x += __shfl_xor(x, 32, 64);
    REDL2(a0) REDL2(a1) REDL2(a2) REDL2(a3)
    REDL2(g0) REDL2(g1) REDL2(g2) REDL2(g3)
    REDL2(q0) REDL2(q1) REDL2(q2) REDL2(q3)
    REDL2(r0) REDL2(r1) REDL2(r2) REDL2(r3)

    if (sub == 0) {
        fvec4 oA = { a0 + bq.x, a1 + bq.y, a2 + bq.z, a3 + bq.w };
        fvec4 oB = { g0 + bq.x, g1 + bq.y, g2 + bq.z, g3 + bq.w };
        fvec4 oC = { q0 + bq.x, q1 + bq.y, q2 + bq.z, q3 + bq.w };
        fvec4 oD = { r0 + bq.x, r1 + bq.y, r2 + bq.z, r3 + bq.w };
        __builtin_nontemporal_store(oA, (fvec4*)(out + (n0+0) * 32 + (e4 << 2)));
        __builtin_nontemporal_store(oB, (fvec4*)(out + (n0+1) * 32 + (e4 << 2)));
        __builtin_nontemporal_store(oC, (fvec4*)(out + (n0+2) * 32 + (e4 << 2)));
        __builtin_nontemporal_store(oD, (fvec4*)(out + (n0+3) * 32 + (e4 << 2)));
    }
}

// ---------------------------------------------------------------------------
extern "C" void kernel_launch(void* const* d_in, const int* in_sizes, int n_in,
                              void* d_out, int out_size, void* d_ws, size_t ws_size,
                              hipStream_t stream)
{
    const float* feats = (const float*)d_in[0];
    const int*   esrc  = (const int*)d_in[1];
    const int*   edst  = (const int*)d_in[2];
    const float* ew    = (const float*)d_in[3];
    const float* W1    = (const float*)d_in[4];
    const float* b1    = (const float*)d_in[5];
    const float* W2    = (const float*)d_in[6];
    const float* b2    = (const float*)d_in[7];
    float* out = (float*)d_out;

    char*          ws    = (char*)d_ws;
    int*           offs  = (int*)ws;
    int*           csrp  = (int*)(ws + OFF_CSR);
    int*           key   = (int*)(ws + OFF_KEY);
    unsigned char* dl    = (unsigned char*)(ws + OFF_DL);
    unsigned char* Yq    = (unsigned char*)(ws + OFF_YQ);
    int*           bcnt  = (int*)(ws + OFF_BCNT);
    int*           boffs = (int*)(ws + OFF_BOFFS);
    int*           gcur  = (int*)(ws + OFF_GCUR);
    __half*        hw    = (__half*)(ws + OFF_HW);   // aliases key (dead post-sort)

    k_zero      <<<1,                  512, 0, stream>>>(bcnt);
    k_bucketcnt <<<NTILES,             256, 0, stream>>>(edst, bcnt);
    k_bucketscan<<<1,                  512, 0, stream>>>(bcnt, boffs, gcur);
    k_bins_g1   <<<NTILES + G1_BLOCKS, 256, 0, stream>>>(edst, esrc, ew, gcur,
                                                         key, dl, feats, W1, Yq);
    k_bucketsort<<<NB,                 256, 0, stream>>>(key, dl, boffs, offs, csrp);
    k_l1        <<<NN / 16,            256, 0, stream>>>(offs, csrp, Yq, b1, W2, hw);
    k_l2        <<<NN / 16,            256, 0, stream>>>(offs, csrp, hw, b2, out);
}